// Round 3
// baseline (11510.857 us; speedup 1.0000x reference)
//
#include <hip/hip_runtime.h>
#include <hip/hip_bf16.h>

// ---------------------------------------------------------------------------
// RSSM scan on MI355X — round 3: L2-streamed weights with ILP + NT isolation.
// scan_kernel: 32 blocks x 1024 thr (16 waves). Block owns 32 batch rows
// (2 row-tiles of 16). Wave w owns output-column tiles:
//   GRU gate-triple nt={w,16+w,32+w}; wz nt=w; q1 nt=w; q2 nt=w&7 (rt=w>>3).
// Weights are STREAMED from L2 each step (per-wave disjoint fragments, b128
// loads, multiple in flight); out/obs/noise use nontemporal ops so the 1 MB
// weight set stays L2-resident. No resident weight VGPRs (round-2 failure:
// 264 VGPR demand vs 128 cap -> rematerialized serial loads, 35us/step).
// MFMA operand-swapped: mfma(W_frag, act_frag) -> D[outcol][batchrow];
// gate biases enter via MFMA C-init; h state in 2x f32x4 regs/lane.
// Fragment addr (shorts): F[rt*4096 + kt*512 + l*8 + j]
//   = X[row=rt*16+(l&15)][k = kt*32 + ((l>>4)&3)*8 + j]
// ---------------------------------------------------------------------------

#define B_   1024
#define L_   256
#define WD_  128
#define AD_  32
#define DD_  256
#define SD_  64
#define HD_  256
#define NA_  17
#define OUT_ 576

typedef __attribute__((ext_vector_type(8))) short bf16x8;
typedef __attribute__((ext_vector_type(4))) float f32x4;
typedef __attribute__((ext_vector_type(2))) float f32x2;

// packed-weight offsets in d_ws (bf16 elements)
#define OFF_WZ   0        // w_in rows 0:64   (64 x 256),  KT=2
#define OFF_WIH  16384    // w_ih            (256 x 768),  KT=8
#define OFF_WHH  212992   // w_hh            (256 x 768),  KT=8
#define OFF_WQ1H 409600   // w_q1 rows 0:256 (256 x 256),  KT=8
#define OFF_WQ1W 475136   // w_q1 rows 256:384(128 x 256), KT=4
#define OFF_WQ2  507904   // w_q2            (256 x 128),  KT=8
#define OFF_WP1  540672   // w_p1            (256 x 256),  KT=8
#define OFF_WP2  606208   // w_p2            (256 x 128),  KT=8
#define PK_TOTAL 638976
#define OFF_ACTP_BYTES (PK_TOTAL * 2)   // float[17*256] after packed weights

__device__ __forceinline__ short f2bf(float f) {
    union { float f; unsigned u; } v; v.f = f;
    unsigned r = (v.u + 0x7fffu + ((v.u >> 16) & 1u)) >> 16;  // RNE
    return (short)r;
}

__device__ __forceinline__ f32x4 mfma16(bf16x8 a, bf16x8 b, f32x4 c) {
    return __builtin_amdgcn_mfma_f32_16x16x32_bf16(a, b, c, 0, 0, 0);
}

__device__ __forceinline__ float sigmoidf_(float x) { return 1.f / (1.f + __expf(-x)); }
__device__ __forceinline__ float tanhf_(float x)    { return 2.f / (1.f + __expf(-2.f * x)) - 1.f; }
__device__ __forceinline__ float softplusf_(float x){ return (x > 20.f) ? x : __logf(1.f + __expf(x)); }

__device__ __forceinline__ f32x4 ntload4(const float* p) { return __builtin_nontemporal_load((const f32x4*)p); }
__device__ __forceinline__ f32x2 ntload2(const float* p) { return __builtin_nontemporal_load((const f32x2*)p); }
__device__ __forceinline__ void ntstore4(float* p, f32x4 v) { __builtin_nontemporal_store(v, (f32x4*)p); }
__device__ __forceinline__ void ntstore2(float* p, f32x2 v) { __builtin_nontemporal_store(v, (f32x2*)p); }

// ---------------------------------------------------------------------------
__global__ void pack_w_kernel(const float* __restrict__ W, short* __restrict__ dst,
                              int KT, int rowOff, int srcN, int total) {
    int tid = blockIdx.x * 256 + threadIdx.x;
    if (tid >= total) return;
    int j    = tid & 7;
    int lane = (tid >> 3) & 63;
    int kt   = (tid >> 9) % KT;
    int nt   = (tid >> 9) / KT;
    int k = kt * 32 + (lane >> 4) * 8 + j;
    int n = nt * 16 + (lane & 15);
    dst[tid] = f2bf(W[(size_t)(rowOff + k) * srcN + n]);
}

__global__ void act_proj_kernel(const float* __restrict__ emb, const float* __restrict__ w_in,
                                const float* __restrict__ b_in, float* __restrict__ actp) {
    int c = threadIdx.x;   // 256
    int a = blockIdx.x;    // 17
    float s = b_in[c];
    for (int i = 0; i < AD_; ++i) s += emb[a * AD_ + i] * w_in[(SD_ + i) * HD_ + c];
    actp[a * HD_ + c] = s;
}

// ---------------------------------------------------------------------------
#define RPB 32
#define NTH 1024

__launch_bounds__(NTH, 4)
__global__ void scan_kernel(const int* __restrict__ actions, const float* __restrict__ obs,
                            const float* __restrict__ noise,
                            const float* __restrict__ b_ih, const float* __restrict__ b_hh,
                            const float* __restrict__ g_ln, const float* __restrict__ beta_ln,
                            const float* __restrict__ b_q1, const float* __restrict__ b_q2,
                            const short* __restrict__ wpk, const float* __restrict__ actp,
                            float* __restrict__ out) {
    __shared__ __align__(16) float xpre[RPB][260];     // 33.3 KB pre-LN f32
    __shared__ __align__(16) float q2v [RPB][132];     // 16.9 KB q2 outputs
    __shared__ __align__(16) float mr  [RPB][2];       // LN mean,rstd
    __shared__ __align__(16) short xF  [8192];         // frag-order acts (2rt x 8kt x 512)
    __shared__ __align__(16) short hF  [2][8192];      // double-buffered h frags
    __shared__ __align__(16) short q1F [8192];
    __shared__ __align__(16) short zF  [2048];         // 2rt x 2kt x 512
    __shared__ __align__(16) short obsF[4096];         // 2rt x 4kt x 512

    const int tid  = threadIdx.x;
    const int w    = tid >> 6;          // wave 0..15
    const int lane = tid & 63;
    const int lrow = lane & 15;         // batch row within tile
    const int lgrp = lane >> 4;
    const int row0 = blockIdx.x * RPB;
    const int c0   = w * 16 + lgrp * 4; // lane's out-col base
    const int foff = lane * 8;          // frag read offset (shorts)
    // frag write base (within a row-tile): value (row=lrow, k=c0+jj)
    const int fwb = (c0 >> 5) * 512 + (lrow + 16 * ((c0 >> 3) & 3)) * 8 + (c0 & 7);
    const f32x4 zero4 = {0.f, 0.f, 0.f, 0.f};

    const short* wz   = wpk + OFF_WZ;
    const short* wih  = wpk + OFF_WIH;
    const short* whh  = wpk + OFF_WHH;
    const short* wq1h = wpk + OFF_WQ1H;
    const short* wq1w = wpk + OFF_WQ1W;
    const short* wq2  = wpk + OFF_WQ2;

    // LN-write mapping: thread owns one full bf16x8 frag of xF (index tid*8)
    const int lnw_row = ((tid >> 9) << 4) + (tid & 15);        // rt*16 + (l&15)
    const int lnw_k0  = (((tid >> 6) & 7) << 5) + (((tid >> 4) & 3) << 3);

    float4 hreg0 = {0.f,0.f,0.f,0.f}, hreg1 = {0.f,0.f,0.f,0.f};
    for (int i = tid; i < 8192; i += NTH) hF[0][i] = 0;
    for (int i = tid; i < 2048; i += NTH) zF[i] = 0;
    __syncthreads();

    int cur = 0;
    for (int t = 0; t < L_; ++t) {
        // ---- Phase A: xpre = z @ Wz + actp[action]; stage obs -> obsF -------
        {
            bf16x8 wz0 = *(const bf16x8*)&wz[(w * 2 + 0) * 512 + foff];
            bf16x8 wz1 = *(const bf16x8*)&wz[(w * 2 + 1) * 512 + foff];
            #pragma unroll
            for (int rt = 0; rt < 2; ++rt) {
                f32x4 a = zero4;
                a = mfma16(wz0, *(const bf16x8*)&zF[rt * 1024 + foff], a);
                a = mfma16(wz1, *(const bf16x8*)&zF[rt * 1024 + 512 + foff], a);
                int act = actions[(row0 + rt * 16 + lrow) * L_ + t];
                f32x4 ap = *(const f32x4*)&actp[act * HD_ + c0];
                *(f32x4*)&xpre[rt * 16 + lrow][c0] = a + ap;
            }
            // obs staging: thread -> (row=tid>>5, cols (tid&31)*4 .. +3)
            int orow = tid >> 5, oc = (tid & 31) * 4;
            f32x4 ov = ntload4(&obs[((size_t)(row0 + orow) * L_ + t) * WD_ + oc]);
            short4 ob4;
            ob4.x = f2bf(ov[0]); ob4.y = f2bf(ov[1]);
            ob4.z = f2bf(ov[2]); ob4.w = f2bf(ov[3]);
            *(short4*)&obsF[(orow >> 4) * 2048 + (oc >> 5) * 512 +
                            ((orow & 15) + 16 * ((oc >> 3) & 3)) * 8 + (oc & 7)] = ob4;
        }
        __syncthreads();   // (1)

        // ---- LN stats: wave w reduces rows 2w (lanes<32) and 2w+1 -----------
        {
            int half = lane >> 5;
            int row  = 2 * w + half;
            int ix   = (lane & 31) * 8;
            f32x4 v0 = *(const f32x4*)&xpre[row][ix];
            f32x4 v1 = *(const f32x4*)&xpre[row][ix + 4];
            float s  = v0[0]+v0[1]+v0[2]+v0[3] + v1[0]+v1[1]+v1[2]+v1[3];
            float ss = v0[0]*v0[0]+v0[1]*v0[1]+v0[2]*v0[2]+v0[3]*v0[3]
                     + v1[0]*v1[0]+v1[1]*v1[1]+v1[2]*v1[2]+v1[3]*v1[3];
            #pragma unroll
            for (int d = 1; d < 32; d <<= 1) {
                s  += __shfl_xor(s, d, 64);
                ss += __shfl_xor(ss, d, 64);
            }
            if ((lane & 31) == 0) {
                float mean = s * (1.f / 256.f);
                float var  = ss * (1.f / 256.f) - mean * mean;
                mr[row][0] = mean;
                mr[row][1] = rsqrtf(var + 1e-5f);
            }
        }
        __syncthreads();   // (2)

        // ---- LN write: thread builds one bf16x8 frag of xF -------------------
        {
            f32x4 xv0 = *(const f32x4*)&xpre[lnw_row][lnw_k0];
            f32x4 xv1 = *(const f32x4*)&xpre[lnw_row][lnw_k0 + 4];
            float mean = mr[lnw_row][0], rstd = mr[lnw_row][1];
            f32x4 g0 = *(const f32x4*)&g_ln[lnw_k0],    g1 = *(const f32x4*)&g_ln[lnw_k0 + 4];
            f32x4 b0 = *(const f32x4*)&beta_ln[lnw_k0], b1 = *(const f32x4*)&beta_ln[lnw_k0 + 4];
            bf16x8 xb;
            #pragma unroll
            for (int j = 0; j < 4; ++j) {
                xb[j]     = f2bf(fmaxf((xv0[j] - mean) * rstd * g0[j] + b0[j], 0.f));
                xb[4 + j] = f2bf(fmaxf((xv1[j] - mean) * rstd * g1[j] + b1[j], 0.f));
            }
            *(bf16x8*)&xF[tid * 8] = xb;
        }
        __syncthreads();   // (3)

        // ---- Phase B: GRU matmuls (fused r/u: ih+hh share acc) ---------------
        f32x4 ar[2] = {zero4, zero4}, au[2] = {zero4, zero4};
        f32x4 anI[2] = {zero4, zero4}, anH[2] = {zero4, zero4};
        {
            const short* hFr = hF[cur];
            #pragma unroll
            for (int kt = 0; kt < 8; ++kt) {
                bf16x8 wri = *(const bf16x8*)&wih[( w        * 8 + kt) * 512 + foff];
                bf16x8 wui = *(const bf16x8*)&wih[((16 + w)  * 8 + kt) * 512 + foff];
                bf16x8 wni = *(const bf16x8*)&wih[((32 + w)  * 8 + kt) * 512 + foff];
                bf16x8 wrh = *(const bf16x8*)&whh[( w        * 8 + kt) * 512 + foff];
                bf16x8 wuh = *(const bf16x8*)&whh[((16 + w)  * 8 + kt) * 512 + foff];
                bf16x8 wnh = *(const bf16x8*)&whh[((32 + w)  * 8 + kt) * 512 + foff];
                #pragma unroll
                for (int rt = 0; rt < 2; ++rt) {
                    bf16x8 xf = *(const bf16x8*)&xF [rt * 4096 + kt * 512 + foff];
                    bf16x8 hf = *(const bf16x8*)&hFr[rt * 4096 + kt * 512 + foff];
                    ar[rt]  = mfma16(wri, xf, ar[rt]);
                    ar[rt]  = mfma16(wrh, hf, ar[rt]);
                    au[rt]  = mfma16(wui, xf, au[rt]);
                    au[rt]  = mfma16(wuh, hf, au[rt]);
                    anI[rt] = mfma16(wni, xf, anI[rt]);
                    anH[rt] = mfma16(wnh, hf, anH[rt]);
                }
            }
        }
        // ---- Phase C (fused, in-wave): gates, h update, hF[cur^1], out-h -----
        {
            f32x4 bir = *(const f32x4*)&b_ih[c0];
            f32x4 biu = *(const f32x4*)&b_ih[256 + c0];
            f32x4 bin = *(const f32x4*)&b_ih[512 + c0];
            f32x4 bhr = *(const f32x4*)&b_hh[c0];
            f32x4 bhu = *(const f32x4*)&b_hh[256 + c0];
            f32x4 bhn = *(const f32x4*)&b_hh[512 + c0];
            short* hFw = hF[cur ^ 1];
            #pragma unroll
            for (int rt = 0; rt < 2; ++rt) {
                float4& hr = rt ? hreg1 : hreg0;
                f32x4 hv4;
                #pragma unroll
                for (int j = 0; j < 4; ++j) {
                    float rr = sigmoidf_(ar[rt][j] + bir[j] + bhr[j]);
                    float uu = sigmoidf_(au[rt][j] + biu[j] + bhu[j]);
                    float nn = tanhf_(anI[rt][j] + bin[j] + rr * (anH[rt][j] + bhn[j]));
                    float ho = (&hr.x)[j];
                    float hv = (1.f - uu) * nn + uu * ho;
                    (&hr.x)[j] = hv;
                    hv4[j] = hv;
                }
                short4 hb;
                hb.x = f2bf(hv4[0]); hb.y = f2bf(hv4[1]);
                hb.z = f2bf(hv4[2]); hb.w = f2bf(hv4[3]);
                *(short4*)&hFw[rt * 4096 + fwb] = hb;
                ntstore4(&out[((size_t)(row0 + rt * 16 + lrow) * L_ + t) * OUT_ + c0], hv4);
            }
        }
        __syncthreads();   // (4)

        // ---- Phase D: q1 = relu(h@Wq1h + obs@Wq1w + b_q1) --------------------
        {
            const short* hFn = hF[cur ^ 1];
            f32x4 a[2] = {zero4, zero4};
            #pragma unroll
            for (int kt = 0; kt < 8; ++kt) {
                bf16x8 wf = *(const bf16x8*)&wq1h[(w * 8 + kt) * 512 + foff];
                #pragma unroll
                for (int rt = 0; rt < 2; ++rt)
                    a[rt] = mfma16(wf, *(const bf16x8*)&hFn[rt * 4096 + kt * 512 + foff], a[rt]);
            }
            #pragma unroll
            for (int kt = 0; kt < 4; ++kt) {
                bf16x8 wf = *(const bf16x8*)&wq1w[(w * 4 + kt) * 512 + foff];
                #pragma unroll
                for (int rt = 0; rt < 2; ++rt)
                    a[rt] = mfma16(wf, *(const bf16x8*)&obsF[rt * 2048 + kt * 512 + foff], a[rt]);
            }
            f32x4 bq = *(const f32x4*)&b_q1[c0];
            #pragma unroll
            for (int rt = 0; rt < 2; ++rt) {
                short4 qb;
                qb.x = f2bf(fmaxf(a[rt][0] + bq[0], 0.f));
                qb.y = f2bf(fmaxf(a[rt][1] + bq[1], 0.f));
                qb.z = f2bf(fmaxf(a[rt][2] + bq[2], 0.f));
                qb.w = f2bf(fmaxf(a[rt][3] + bq[3], 0.f));
                *(short4*)&q1F[rt * 4096 + fwb] = qb;
            }
        }
        __syncthreads();   // (5)

        // ---- Phase E: q2 = q1 @ Wq2 + b_q2 (wave -> nt=w&7, rt=w>>3) ---------
        {
            int nt = w & 7, rt = w >> 3;
            f32x4 a = zero4;
            #pragma unroll
            for (int kt = 0; kt < 8; ++kt) {
                bf16x8 wf = *(const bf16x8*)&wq2[(nt * 8 + kt) * 512 + foff];
                a = mfma16(wf, *(const bf16x8*)&q1F[rt * 4096 + kt * 512 + foff], a);
            }
            int colb = nt * 16 + lgrp * 4;
            f32x4 bq = *(const f32x4*)&b_q2[colb];
            *(f32x4*)&q2v[rt * 16 + lrow][colb] = a + bq;
        }
        __syncthreads();   // (6)

        // ---- Phase F: z sample; out z/qm/qs; zF for next step ----------------
        {
            int row = tid >> 5, n2 = (tid & 31) * 2;
            f32x2 qm2, ql2;
            qm2[0] = q2v[row][n2];      qm2[1] = q2v[row][n2 + 1];
            ql2[0] = q2v[row][64 + n2]; ql2[1] = q2v[row][64 + n2 + 1];
            f32x2 eps = ntload2(&noise[((size_t)(row0 + row) * L_ + t) * SD_ + n2]);
            f32x2 qs2, zv2;
            qs2[0] = softplusf_(ql2[0]) + 0.1f;
            qs2[1] = softplusf_(ql2[1]) + 0.1f;
            zv2[0] = qm2[0] + qs2[0] * eps[0];
            zv2[1] = qm2[1] + qs2[1] * eps[1];
            unsigned zpk = (unsigned)(unsigned short)f2bf(zv2[0])
                         | ((unsigned)(unsigned short)f2bf(zv2[1]) << 16);
            *(unsigned*)&zF[(row >> 4) * 1024 + (n2 >> 5) * 512 +
                            ((row & 15) + 16 * ((n2 >> 3) & 3)) * 8 + (n2 & 7)] = zpk;
            size_t ob = ((size_t)(row0 + row) * L_ + t) * OUT_;
            ntstore2(&out[ob + 256 + n2], zv2);
            ntstore2(&out[ob + 448 + n2], qm2);
            ntstore2(&out[ob + 512 + n2], qs2);
        }
        __syncthreads();   // (7)
        cur ^= 1;
    }
}

// ---------------------------------------------------------------------------
// Deferred prior head: pstats = relu(h @ w_p1 + b_p1) @ w_p2 + b_p2
__launch_bounds__(256, 2)
__global__ void prior_kernel(const float* __restrict__ b_p1, const float* __restrict__ b_p2,
                             const short* __restrict__ wpk, float* __restrict__ out) {
    const short* wp1 = wpk + OFF_WP1;
    const short* wp2 = wpk + OFF_WP2;
    __shared__ __align__(16) short p1b[4][16][264];
    const int tid = threadIdx.x, wid = tid >> 6, lane = tid & 63;
    const int lrow = lane & 15, lgrp = lane >> 4;
    const size_t rbase = (size_t)blockIdx.x * 64 + wid * 16;
    const f32x4 zero4 = {0.f, 0.f, 0.f, 0.f};

    f32x4 acc[16];
    #pragma unroll
    for (int nt = 0; nt < 16; ++nt) acc[nt] = zero4;
    for (int kt = 0; kt < 8; ++kt) {
        const f32x4* hp = (const f32x4*)&out[(rbase + lrow) * OUT_ + kt * 32 + lgrp * 8];
        f32x4 h0 = hp[0], h1 = hp[1];
        bf16x8 a;
        a[0] = f2bf(h0[0]); a[1] = f2bf(h0[1]); a[2] = f2bf(h0[2]); a[3] = f2bf(h0[3]);
        a[4] = f2bf(h1[0]); a[5] = f2bf(h1[1]); a[6] = f2bf(h1[2]); a[7] = f2bf(h1[3]);
        #pragma unroll
        for (int nt = 0; nt < 16; ++nt) {
            bf16x8 b = *(const bf16x8*)&wp1[(nt * 8 + kt) * 512 + lane * 8];
            acc[nt] = mfma16(a, b, acc[nt]);
        }
    }
    #pragma unroll
    for (int nt = 0; nt < 16; ++nt) {
        int colb = nt * 16 + lrow;
        #pragma unroll
        for (int j = 0; j < 4; ++j)
            p1b[wid][lgrp * 4 + j][colb] = f2bf(fmaxf(acc[nt][j] + b_p1[colb], 0.f));
    }
    __syncthreads();

    f32x4 acc2[8];
    #pragma unroll
    for (int nt = 0; nt < 8; ++nt) acc2[nt] = zero4;
    for (int kt = 0; kt < 8; ++kt) {
        bf16x8 a = *(const bf16x8*)&p1b[wid][lrow][kt * 32 + lgrp * 8];
        #pragma unroll
        for (int nt = 0; nt < 8; ++nt) {
            bf16x8 b = *(const bf16x8*)&wp2[(nt * 8 + kt) * 512 + lane * 8];
            acc2[nt] = mfma16(a, b, acc2[nt]);
        }
    }
    #pragma unroll
    for (int nt = 0; nt < 8; ++nt) {
        #pragma unroll
        for (int j = 0; j < 4; ++j) {
            size_t rw = rbase + lgrp * 4 + j;
            int col = nt * 16 + lrow;
            float v = acc2[nt][j] + b_p2[col];
            if (col < 64) out[rw * OUT_ + 320 + col] = v;
            else          out[rw * OUT_ + 384 + (col - 64)] = softplusf_(v) + 0.1f;
        }
    }
}

// ---------------------------------------------------------------------------
extern "C" void kernel_launch(void* const* d_in, const int* in_sizes, int n_in,
                              void* d_out, int out_size, void* d_ws, size_t ws_size,
                              hipStream_t stream) {
    const int*   actions = (const int*)  d_in[0];
    const float* obs     = (const float*)d_in[1];
    const float* noise   = (const float*)d_in[2];
    const float* emb     = (const float*)d_in[3];
    const float* w_in    = (const float*)d_in[4];
    const float* b_in    = (const float*)d_in[5];
    const float* g_ln    = (const float*)d_in[6];
    const float* beta_ln = (const float*)d_in[7];
    const float* w_ih    = (const float*)d_in[8];
    const float* b_ih    = (const float*)d_in[9];
    const float* w_hh    = (const float*)d_in[10];
    const float* b_hh    = (const float*)d_in[11];
    const float* w_p1    = (const float*)d_in[12];
    const float* b_p1    = (const float*)d_in[13];
    const float* w_p2    = (const float*)d_in[14];
    const float* b_p2    = (const float*)d_in[15];
    const float* w_q1    = (const float*)d_in[16];
    const float* b_q1    = (const float*)d_in[17];
    const float* w_q2    = (const float*)d_in[18];
    const float* b_q2    = (const float*)d_in[19];

    short* wpk  = (short*)d_ws;
    float* actp = (float*)((char*)d_ws + OFF_ACTP_BYTES);
    float* out  = (float*)d_out;

    auto packLaunch = [&](const float* W, int off, int KT, int rowOff, int srcN, int total) {
        pack_w_kernel<<<(total + 255) / 256, 256, 0, stream>>>(W, wpk + off, KT, rowOff, srcN, total);
    };
    packLaunch(w_in, OFF_WZ,    2, 0,   256, 64 * 256);
    packLaunch(w_ih, OFF_WIH,   8, 0,   768, 256 * 768);
    packLaunch(w_hh, OFF_WHH,   8, 0,   768, 256 * 768);
    packLaunch(w_q1, OFF_WQ1H,  8, 0,   256, 256 * 256);
    packLaunch(w_q1, OFF_WQ1W,  4, 256, 256, 128 * 256);
    packLaunch(w_q2, OFF_WQ2,   8, 0,   128, 256 * 128);
    packLaunch(w_p1, OFF_WP1,   8, 0,   256, 256 * 256);
    packLaunch(w_p2, OFF_WP2,   8, 0,   128, 256 * 128);
    act_proj_kernel<<<NA_, 256, 0, stream>>>(emb, w_in, b_in, actp);

    scan_kernel<<<B_ / RPB, NTH, 0, stream>>>(actions, obs, noise, b_ih, b_hh,
                                              g_ln, beta_ln, b_q1, b_q2, wpk, actp, out);
    prior_kernel<<<(B_ * L_) / 64, 256, 0, stream>>>(b_p1, b_p2, wpk, out);
}

// Round 4
// 4759.333 us; speedup vs baseline: 2.4186x; 2.4186x over previous
//
#include <hip/hip_runtime.h>
#include <hip/hip_bf16.h>

// ---------------------------------------------------------------------------
// RSSM scan on MI355X — round 4: manual vmcnt-counted weight prefetch.
// 32 blocks x 1024 thr (16 waves, 4/SIMD), block owns 32 batch rows (2 rt).
// Wave w owns GRU gate-triple nt={w,16+w,32+w}, q1 nt=w, q2 (nt=w&7, rt=w>>3).
// Weight loads = inline-asm global_load_dwordx4 (SGPR base + lane*16 voff),
// pipelined with s_waitcnt vmcnt(N) + sched_barrier(0) (guide rule #18).
// GRU: 2-buffer x 6-frag, vmcnt(6)/kt. q1: 12 upfront, vmcnt(8/4/0).
// q2: 8 upfront, vmcnt(4/0). Phases drain at barriers -> counts never mix
// with compiler VMEM (biases/LN in LDS; asm-free phases keep compiler loads).
// MFMA operand-swapped: mfma(W_frag, act_frag) -> D[outcol][batchrow].
// Frag addr (shorts): F[rt*4096 + kt*512 + l*8 + j]
//   = X[row=rt*16+(l&15)][k = kt*32 + ((l>>4)&3)*8 + j]
// ---------------------------------------------------------------------------

#define B_   1024
#define L_   256
#define WD_  128
#define AD_  32
#define DD_  256
#define SD_  64
#define HD_  256
#define NA_  17
#define OUT_ 576

typedef __attribute__((ext_vector_type(8))) short bf16x8;
typedef __attribute__((ext_vector_type(4))) float f32x4;
typedef __attribute__((ext_vector_type(2))) float f32x2;

// packed-weight offsets in d_ws (bf16 elements)
#define OFF_WZ   0        // w_in rows 0:64   (64 x 256),  KT=2
#define OFF_WIH  16384    // w_ih            (256 x 768),  KT=8
#define OFF_WHH  212992   // w_hh            (256 x 768),  KT=8
#define OFF_WQ1H 409600   // w_q1 rows 0:256 (256 x 256),  KT=8
#define OFF_WQ1W 475136   // w_q1 rows 256:384(128 x 256), KT=4
#define OFF_WQ2  507904   // w_q2            (256 x 128),  KT=8
#define OFF_WP1  540672   // w_p1            (256 x 256),  KT=8
#define OFF_WP2  606208   // w_p2            (256 x 128),  KT=8
#define PK_TOTAL 638976
#define OFF_ACTP_BYTES (PK_TOTAL * 2)

__device__ __forceinline__ short f2bf(float f) {
    union { float f; unsigned u; } v; v.f = f;
    unsigned r = (v.u + 0x7fffu + ((v.u >> 16) & 1u)) >> 16;  // RNE
    return (short)r;
}

__device__ __forceinline__ f32x4 mfma16(bf16x8 a, bf16x8 b, f32x4 c) {
    return __builtin_amdgcn_mfma_f32_16x16x32_bf16(a, b, c, 0, 0, 0);
}

__device__ __forceinline__ float sigmoidf_(float x) { return 1.f / (1.f + __expf(-x)); }
__device__ __forceinline__ float tanhf_(float x)    { return 2.f / (1.f + __expf(-2.f * x)) - 1.f; }
__device__ __forceinline__ float softplusf_(float x){ return (x > 20.f) ? x : __logf(1.f + __expf(x)); }

__device__ __forceinline__ f32x4 ntload4(const float* p) { return __builtin_nontemporal_load((const f32x4*)p); }
__device__ __forceinline__ f32x2 ntload2(const float* p) { return __builtin_nontemporal_load((const f32x2*)p); }
__device__ __forceinline__ void ntstore4(float* p, f32x4 v) { __builtin_nontemporal_store(v, (f32x4*)p); }
__device__ __forceinline__ void ntstore2(float* p, f32x2 v) { __builtin_nontemporal_store(v, (f32x2*)p); }

// async weight load: SGPR base (wave-uniform) + VGPR byte offset, vmcnt-counted
template<int IMM>
__device__ __forceinline__ bf16x8 gload(const short* sbase, unsigned voff) {
    bf16x8 d;
    if constexpr (IMM == 0) {
        asm volatile("global_load_dwordx4 %0, %1, %2"
                     : "=v"(d) : "v"(voff), "s"(sbase));
    } else {
        asm volatile("global_load_dwordx4 %0, %1, %2 offset:%3"
                     : "=v"(d) : "v"(voff), "s"(sbase), "i"(IMM));
    }
    return d;
}

#define VMW(N) do { asm volatile("s_waitcnt vmcnt(" #N ")" ::: "memory"); \
                    __builtin_amdgcn_sched_barrier(0); } while (0)

// ---------------------------------------------------------------------------
__global__ void pack_w_kernel(const float* __restrict__ W, short* __restrict__ dst,
                              int KT, int rowOff, int srcN, int total) {
    int tid = blockIdx.x * 256 + threadIdx.x;
    if (tid >= total) return;
    int j    = tid & 7;
    int lane = (tid >> 3) & 63;
    int kt   = (tid >> 9) % KT;
    int nt   = (tid >> 9) / KT;
    int k = kt * 32 + (lane >> 4) * 8 + j;
    int n = nt * 16 + (lane & 15);
    dst[tid] = f2bf(W[(size_t)(rowOff + k) * srcN + n]);
}

__global__ void act_proj_kernel(const float* __restrict__ emb, const float* __restrict__ w_in,
                                const float* __restrict__ b_in, float* __restrict__ actp) {
    int c = threadIdx.x;   // 256
    int a = blockIdx.x;    // 17
    float s = b_in[c];
    for (int i = 0; i < AD_; ++i) s += emb[a * AD_ + i] * w_in[(SD_ + i) * HD_ + c];
    actp[a * HD_ + c] = s;
}

// ---------------------------------------------------------------------------
#define RPB 32
#define NTH 1024

template<int KT>
__device__ __forceinline__ void issue6(bf16x8 (&buf)[6],
        const short* ri, const short* ui, const short* ni,
        const short* rh, const short* uh, const short* nh, unsigned voff) {
    constexpr int ADD = (KT >= 4) ? 2048 : 0;   // shorts
    constexpr int IMM = (KT & 3) * 1024;        // bytes
    buf[0] = gload<IMM>(ri + ADD, voff);
    buf[1] = gload<IMM>(ui + ADD, voff);
    buf[2] = gload<IMM>(ni + ADD, voff);
    buf[3] = gload<IMM>(rh + ADD, voff);
    buf[4] = gload<IMM>(uh + ADD, voff);
    buf[5] = gload<IMM>(nh + ADD, voff);
}

__launch_bounds__(NTH, 4)
__global__ void scan_kernel(const int* __restrict__ actions, const float* __restrict__ obs,
                            const float* __restrict__ noise,
                            const float* __restrict__ b_ih, const float* __restrict__ b_hh,
                            const float* __restrict__ g_ln, const float* __restrict__ beta_ln,
                            const float* __restrict__ b_q1, const float* __restrict__ b_q2,
                            const short* __restrict__ wpk, const float* __restrict__ actp,
                            float* __restrict__ out) {
    __shared__ __align__(16) float ps_s [32][16];
    __shared__ __align__(16) float ps_ss[32][16];
    __shared__ __align__(16) float mr[32][2];
    __shared__ __align__(16) float q2v[RPB][132];
    __shared__ __align__(16) short xF  [8192];
    __shared__ __align__(16) short hF  [8192];
    __shared__ __align__(16) short q1F [8192];
    __shared__ __align__(16) short zF  [2048];
    __shared__ __align__(16) short obsF[4096];
    __shared__ __align__(16) float bsumr_l[256], bsumu_l[256], bihn_l[256], bhhn_l[256];
    __shared__ __align__(16) float bq1_l[256], lng_l[256], lnb_l[256], bq2_l[128];

    const int tid  = threadIdx.x;
    const int w    = tid >> 6;          // wave 0..15
    const int lane = tid & 63;
    const int lrow = lane & 15;
    const int lgrp = lane >> 4;
    const int row0 = blockIdx.x * RPB;
    const int c0   = w * 16 + lgrp * 4;
    const int foff = lane * 8;          // frag read offset (shorts)
    const int fwb  = (c0 >> 5) * 512 + (lrow + 16 * ((c0 >> 3) & 3)) * 8 + (c0 & 7);
    const f32x4 zero4 = {0.f, 0.f, 0.f, 0.f};

    const int wu = __builtin_amdgcn_readfirstlane(w);
    const unsigned voff = (unsigned)lane * 16u;
    const short* wz   = wpk + OFF_WZ;
    const short* sbri = wpk + OFF_WIH  + (wu * 8) * 512;
    const short* sbui = wpk + OFF_WIH  + ((16 + wu) * 8) * 512;
    const short* sbni = wpk + OFF_WIH  + ((32 + wu) * 8) * 512;
    const short* sbrh = wpk + OFF_WHH  + (wu * 8) * 512;
    const short* sbuh = wpk + OFF_WHH  + ((16 + wu) * 8) * 512;
    const short* sbnh = wpk + OFF_WHH  + ((32 + wu) * 8) * 512;
    const short* sbq1h = wpk + OFF_WQ1H + (wu * 8) * 512;
    const short* sbq1w = wpk + OFF_WQ1W + (wu * 4) * 512;
    const short* sbq2  = wpk + OFF_WQ2  + ((wu & 7) * 8) * 512;
    const int ert = wu >> 3;   // q2 row-tile

    // ---- prologue: biases/LN params -> LDS; zero state ----------------------
    if (tid < 256) {
        bsumr_l[tid] = b_ih[tid] + b_hh[tid];
        bsumu_l[tid] = b_ih[256 + tid] + b_hh[256 + tid];
        bihn_l[tid]  = b_ih[512 + tid];
        bhhn_l[tid]  = b_hh[512 + tid];
        bq1_l[tid]   = b_q1[tid];
        lng_l[tid]   = g_ln[tid];
        lnb_l[tid]   = beta_ln[tid];
    } else if (tid < 384) {
        bq2_l[tid - 256] = b_q2[tid - 256];
    }
    for (int i = tid; i < 8192; i += NTH) hF[i] = 0;
    for (int i = tid; i < 2048; i += NTH) zF[i] = 0;
    f32x4 hreg[2] = {zero4, zero4};
    __syncthreads();

    for (int t = 0; t < L_; ++t) {
        // ---- Phase A: xpre = z@Wz + actp[act] (regs); LN partials; obs stage --
        f32x4 xp0, xp1;
        {
            bf16x8 Wz0 = *(const bf16x8*)&wz[(wu * 2 + 0) * 512 + foff];
            bf16x8 Wz1 = *(const bf16x8*)&wz[(wu * 2 + 1) * 512 + foff];
            f32x4 a0 = zero4, a1 = zero4;
            a0 = mfma16(Wz0, *(const bf16x8*)&zF[foff], a0);
            a0 = mfma16(Wz1, *(const bf16x8*)&zF[512 + foff], a0);
            a1 = mfma16(Wz0, *(const bf16x8*)&zF[1024 + foff], a1);
            a1 = mfma16(Wz1, *(const bf16x8*)&zF[1536 + foff], a1);
            int act0 = actions[(row0 + lrow) * L_ + t];
            int act1 = actions[(row0 + 16 + lrow) * L_ + t];
            xp0 = a0 + *(const f32x4*)&actp[act0 * HD_ + c0];
            xp1 = a1 + *(const f32x4*)&actp[act1 * HD_ + c0];
            float s0 = xp0[0] + xp0[1] + xp0[2] + xp0[3];
            float q0 = xp0[0]*xp0[0] + xp0[1]*xp0[1] + xp0[2]*xp0[2] + xp0[3]*xp0[3];
            float s1 = xp1[0] + xp1[1] + xp1[2] + xp1[3];
            float q1 = xp1[0]*xp1[0] + xp1[1]*xp1[1] + xp1[2]*xp1[2] + xp1[3]*xp1[3];
            s0 += __shfl_xor(s0, 16, 64); s0 += __shfl_xor(s0, 32, 64);
            q0 += __shfl_xor(q0, 16, 64); q0 += __shfl_xor(q0, 32, 64);
            s1 += __shfl_xor(s1, 16, 64); s1 += __shfl_xor(s1, 32, 64);
            q1 += __shfl_xor(q1, 16, 64); q1 += __shfl_xor(q1, 32, 64);
            if (lgrp == 0) {
                ps_s [lrow][w] = s0; ps_ss[lrow][w] = q0;
                ps_s [16 + lrow][w] = s1; ps_ss[16 + lrow][w] = q1;
            }
            // obs staging
            int orow = tid >> 5, oc = (tid & 31) * 4;
            f32x4 ov = ntload4(&obs[((size_t)(row0 + orow) * L_ + t) * WD_ + oc]);
            short4 o4;
            o4.x = f2bf(ov[0]); o4.y = f2bf(ov[1]); o4.z = f2bf(ov[2]); o4.w = f2bf(ov[3]);
            *(short4*)&obsF[(orow >> 4) * 2048 + (oc >> 5) * 512 +
                            ((orow & 15) + 16 * ((oc >> 3) & 3)) * 8 + (oc & 7)] = o4;
        }
        __syncthreads();   // (1)

        if (tid < 32) {    // LN final reduce: 32 rows
            f32x4 sa = *(const f32x4*)&ps_s[tid][0]  + *(const f32x4*)&ps_s[tid][4]
                     + *(const f32x4*)&ps_s[tid][8]  + *(const f32x4*)&ps_s[tid][12];
            f32x4 qa = *(const f32x4*)&ps_ss[tid][0] + *(const f32x4*)&ps_ss[tid][4]
                     + *(const f32x4*)&ps_ss[tid][8] + *(const f32x4*)&ps_ss[tid][12];
            float s = sa[0] + sa[1] + sa[2] + sa[3];
            float q = qa[0] + qa[1] + qa[2] + qa[3];
            float mean = s * (1.f / 256.f);
            float var  = q * (1.f / 256.f) - mean * mean;
            mr[tid][0] = mean;
            mr[tid][1] = rsqrtf(var + 1e-5f);
        }
        __syncthreads();   // (2)

        {   // LN normalize (in-reg) -> xF
            f32x4 g  = *(const f32x4*)&lng_l[c0];
            f32x4 bb = *(const f32x4*)&lnb_l[c0];
            float m0 = mr[lrow][0],      r0 = mr[lrow][1];
            float m1 = mr[16 + lrow][0], r1 = mr[16 + lrow][1];
            short4 x0, x1;
            x0.x = f2bf(fmaxf((xp0[0] - m0) * r0 * g[0] + bb[0], 0.f));
            x0.y = f2bf(fmaxf((xp0[1] - m0) * r0 * g[1] + bb[1], 0.f));
            x0.z = f2bf(fmaxf((xp0[2] - m0) * r0 * g[2] + bb[2], 0.f));
            x0.w = f2bf(fmaxf((xp0[3] - m0) * r0 * g[3] + bb[3], 0.f));
            x1.x = f2bf(fmaxf((xp1[0] - m1) * r1 * g[0] + bb[0], 0.f));
            x1.y = f2bf(fmaxf((xp1[1] - m1) * r1 * g[1] + bb[1], 0.f));
            x1.z = f2bf(fmaxf((xp1[2] - m1) * r1 * g[2] + bb[2], 0.f));
            x1.w = f2bf(fmaxf((xp1[3] - m1) * r1 * g[3] + bb[3], 0.f));
            *(short4*)&xF[fwb] = x0;
            *(short4*)&xF[4096 + fwb] = x1;
        }
        __syncthreads();   // (3)

        // ---- Phase B: GRU matmuls, pipelined weight streams -------------------
        f32x4 ar[2] = {zero4, zero4}, au[2] = {zero4, zero4};
        f32x4 aI[2] = {zero4, zero4}, aH[2] = {zero4, zero4};
        {
            bf16x8 wb0[6], wb1[6];
            issue6<0>(wb0, sbri, sbui, sbni, sbrh, sbuh, sbnh, voff);
            issue6<1>(wb1, sbri, sbui, sbni, sbrh, sbuh, sbnh, voff);

#define GRU_KT(KT, WBUF, WN) do { \
            VMW(WN); \
            { \
                bf16x8 xf0 = *(const bf16x8*)&xF[(KT) * 512 + foff]; \
                bf16x8 hf0 = *(const bf16x8*)&hF[(KT) * 512 + foff]; \
                ar[0] = mfma16(WBUF[0], xf0, ar[0]); ar[0] = mfma16(WBUF[3], hf0, ar[0]); \
                au[0] = mfma16(WBUF[1], xf0, au[0]); au[0] = mfma16(WBUF[4], hf0, au[0]); \
                aI[0] = mfma16(WBUF[2], xf0, aI[0]); aH[0] = mfma16(WBUF[5], hf0, aH[0]); \
                bf16x8 xf1 = *(const bf16x8*)&xF[4096 + (KT) * 512 + foff]; \
                bf16x8 hf1 = *(const bf16x8*)&hF[4096 + (KT) * 512 + foff]; \
                ar[1] = mfma16(WBUF[0], xf1, ar[1]); ar[1] = mfma16(WBUF[3], hf1, ar[1]); \
                au[1] = mfma16(WBUF[1], xf1, au[1]); au[1] = mfma16(WBUF[4], hf1, au[1]); \
                aI[1] = mfma16(WBUF[2], xf1, aI[1]); aH[1] = mfma16(WBUF[5], hf1, aH[1]); \
            } \
            if constexpr ((KT) + 2 < 8) \
                issue6<(KT) + 2>(WBUF, sbri, sbui, sbni, sbrh, sbuh, sbnh, voff); \
        } while (0)

            GRU_KT(0, wb0, 6);
            GRU_KT(1, wb1, 6);
            GRU_KT(2, wb0, 6);
            GRU_KT(3, wb1, 6);
            GRU_KT(4, wb0, 6);
            GRU_KT(5, wb1, 6);
            GRU_KT(6, wb0, 6);
            GRU_KT(7, wb1, 0);
#undef GRU_KT
        }
        __syncthreads();   // (4) all hF reads done before rewrite

        // ---- Phase C: gates, h update, hF write, out-h -------------------------
        {
            f32x4 bsr = *(const f32x4*)&bsumr_l[c0];
            f32x4 bsu = *(const f32x4*)&bsumu_l[c0];
            f32x4 bin = *(const f32x4*)&bihn_l[c0];
            f32x4 bhn = *(const f32x4*)&bhhn_l[c0];
            #pragma unroll
            for (int rt = 0; rt < 2; ++rt) {
                f32x4 hv;
                #pragma unroll
                for (int j = 0; j < 4; ++j) {
                    float rr = sigmoidf_(ar[rt][j] + bsr[j]);
                    float uu = sigmoidf_(au[rt][j] + bsu[j]);
                    float nn = tanhf_(aI[rt][j] + bin[j] + rr * (aH[rt][j] + bhn[j]));
                    hv[j] = (1.f - uu) * nn + uu * hreg[rt][j];
                }
                hreg[rt] = hv;
                short4 hb;
                hb.x = f2bf(hv[0]); hb.y = f2bf(hv[1]); hb.z = f2bf(hv[2]); hb.w = f2bf(hv[3]);
                *(short4*)&hF[rt * 4096 + fwb] = hb;
                ntstore4(&out[((size_t)(row0 + rt * 16 + lrow) * L_ + t) * OUT_ + c0], hv);
            }
        }
        __syncthreads();   // (5)

        // ---- Phase D: q1 = relu(h@Wq1h + obs@Wq1w + b_q1) ----------------------
        {
            bf16x8 db[12];
            db[0]  = gload<0>   (sbq1h, voff);
            db[1]  = gload<1024>(sbq1h, voff);
            db[2]  = gload<2048>(sbq1h, voff);
            db[3]  = gload<3072>(sbq1h, voff);
            db[4]  = gload<0>   (sbq1h + 2048, voff);
            db[5]  = gload<1024>(sbq1h + 2048, voff);
            db[6]  = gload<2048>(sbq1h + 2048, voff);
            db[7]  = gload<3072>(sbq1h + 2048, voff);
            db[8]  = gload<0>   (sbq1w, voff);
            db[9]  = gload<1024>(sbq1w, voff);
            db[10] = gload<2048>(sbq1w, voff);
            db[11] = gload<3072>(sbq1w, voff);
            f32x4 aq[2] = {zero4, zero4};
#define Q1H(KT) { \
            bf16x8 h0 = *(const bf16x8*)&hF[(KT) * 512 + foff]; \
            bf16x8 h1 = *(const bf16x8*)&hF[4096 + (KT) * 512 + foff]; \
            aq[0] = mfma16(db[KT], h0, aq[0]); \
            aq[1] = mfma16(db[KT], h1, aq[1]); }
#define Q1W(KK) { \
            bf16x8 o0 = *(const bf16x8*)&obsF[(KK) * 512 + foff]; \
            bf16x8 o1 = *(const bf16x8*)&obsF[2048 + (KK) * 512 + foff]; \
            aq[0] = mfma16(db[8 + (KK)], o0, aq[0]); \
            aq[1] = mfma16(db[8 + (KK)], o1, aq[1]); }
            VMW(8);
            Q1H(0) Q1H(1) Q1H(2) Q1H(3)
            VMW(4);
            Q1H(4) Q1H(5) Q1H(6) Q1H(7)
            VMW(0);
            Q1W(0) Q1W(1) Q1W(2) Q1W(3)
#undef Q1H
#undef Q1W
            f32x4 bq = *(const f32x4*)&bq1_l[c0];
            #pragma unroll
            for (int rt = 0; rt < 2; ++rt) {
                f32x4 a = aq[rt];
                short4 qb;
                qb.x = f2bf(fmaxf(a[0] + bq[0], 0.f));
                qb.y = f2bf(fmaxf(a[1] + bq[1], 0.f));
                qb.z = f2bf(fmaxf(a[2] + bq[2], 0.f));
                qb.w = f2bf(fmaxf(a[3] + bq[3], 0.f));
                *(short4*)&q1F[rt * 4096 + fwb] = qb;
            }
        }
        __syncthreads();   // (6)

        // ---- Phase E: q2 = q1 @ Wq2 + b_q2 (nt=w&7, rt=w>>3) -------------------
        {
            bf16x8 eb[8];
            eb[0] = gload<0>   (sbq2, voff);
            eb[1] = gload<1024>(sbq2, voff);
            eb[2] = gload<2048>(sbq2, voff);
            eb[3] = gload<3072>(sbq2, voff);
            eb[4] = gload<0>   (sbq2 + 2048, voff);
            eb[5] = gload<1024>(sbq2 + 2048, voff);
            eb[6] = gload<2048>(sbq2 + 2048, voff);
            eb[7] = gload<3072>(sbq2 + 2048, voff);
            f32x4 a = zero4;
#define Q2K(KT) { \
            bf16x8 qf = *(const bf16x8*)&q1F[ert * 4096 + (KT) * 512 + foff]; \
            a = mfma16(eb[KT], qf, a); }
            VMW(4);
            Q2K(0) Q2K(1) Q2K(2) Q2K(3)
            VMW(0);
            Q2K(4) Q2K(5) Q2K(6) Q2K(7)
#undef Q2K
            int cb = (w & 7) * 16 + lgrp * 4;
            f32x4 b2 = *(const f32x4*)&bq2_l[cb];
            *(f32x4*)&q2v[ert * 16 + lrow][cb] = a + b2;
        }
        __syncthreads();   // (7)

        // ---- Phase F: z sample; out z/qm/qs; zF -------------------------------
        {
            int row = tid >> 5, n2 = (tid & 31) * 2;
            float qm0 = q2v[row][n2],      qm1 = q2v[row][n2 + 1];
            float ql0 = q2v[row][64 + n2], ql1 = q2v[row][64 + n2 + 1];
            f32x2 eps = ntload2(&noise[((size_t)(row0 + row) * L_ + t) * SD_ + n2]);
            float qs0 = softplusf_(ql0) + 0.1f, qs1 = softplusf_(ql1) + 0.1f;
            float zv0 = qm0 + qs0 * eps[0],     zv1 = qm1 + qs1 * eps[1];
            unsigned zpk = (unsigned)(unsigned short)f2bf(zv0)
                         | ((unsigned)(unsigned short)f2bf(zv1) << 16);
            *(unsigned*)&zF[(row >> 4) * 1024 + (n2 >> 5) * 512 +
                            ((row & 15) + 16 * ((n2 >> 3) & 3)) * 8 + (n2 & 7)] = zpk;
            size_t ob = ((size_t)(row0 + row) * L_ + t) * OUT_;
            f32x2 z2; z2[0] = zv0; z2[1] = zv1;
            f32x2 m2; m2[0] = qm0; m2[1] = qm1;
            f32x2 s2; s2[0] = qs0; s2[1] = qs1;
            ntstore2(&out[ob + 256 + n2], z2);
            ntstore2(&out[ob + 448 + n2], m2);
            ntstore2(&out[ob + 512 + n2], s2);
        }
        __syncthreads();   // (8)
    }
}

// ---------------------------------------------------------------------------
// Deferred prior head: pstats = relu(h @ w_p1 + b_p1) @ w_p2 + b_p2
__launch_bounds__(256, 2)
__global__ void prior_kernel(const float* __restrict__ b_p1, const float* __restrict__ b_p2,
                             const short* __restrict__ wpk, float* __restrict__ out) {
    const short* wp1 = wpk + OFF_WP1;
    const short* wp2 = wpk + OFF_WP2;
    __shared__ __align__(16) short p1b[4][16][264];
    const int tid = threadIdx.x, wid = tid >> 6, lane = tid & 63;
    const int lrow = lane & 15, lgrp = lane >> 4;
    const size_t rbase = (size_t)blockIdx.x * 64 + wid * 16;
    const f32x4 zero4 = {0.f, 0.f, 0.f, 0.f};

    f32x4 acc[16];
    #pragma unroll
    for (int nt = 0; nt < 16; ++nt) acc[nt] = zero4;
    for (int kt = 0; kt < 8; ++kt) {
        const f32x4* hp = (const f32x4*)&out[(rbase + lrow) * OUT_ + kt * 32 + lgrp * 8];
        f32x4 h0 = hp[0], h1 = hp[1];
        bf16x8 a;
        a[0] = f2bf(h0[0]); a[1] = f2bf(h0[1]); a[2] = f2bf(h0[2]); a[3] = f2bf(h0[3]);
        a[4] = f2bf(h1[0]); a[5] = f2bf(h1[1]); a[6] = f2bf(h1[2]); a[7] = f2bf(h1[3]);
        #pragma unroll
        for (int nt = 0; nt < 16; ++nt) {
            bf16x8 b = *(const bf16x8*)&wp1[(nt * 8 + kt) * 512 + lane * 8];
            acc[nt] = mfma16(a, b, acc[nt]);
        }
    }
    #pragma unroll
    for (int nt = 0; nt < 16; ++nt) {
        int colb = nt * 16 + lrow;
        #pragma unroll
        for (int j = 0; j < 4; ++j)
            p1b[wid][lgrp * 4 + j][colb] = f2bf(fmaxf(acc[nt][j] + b_p1[colb], 0.f));
    }
    __syncthreads();

    f32x4 acc2[8];
    #pragma unroll
    for (int nt = 0; nt < 8; ++nt) acc2[nt] = zero4;
    for (int kt = 0; kt < 8; ++kt) {
        bf16x8 a = *(const bf16x8*)&p1b[wid][lrow][kt * 32 + lgrp * 8];
        #pragma unroll
        for (int nt = 0; nt < 8; ++nt) {
            bf16x8 b = *(const bf16x8*)&wp2[(nt * 8 + kt) * 512 + lane * 8];
            acc2[nt] = mfma16(a, b, acc2[nt]);
        }
    }
    #pragma unroll
    for (int nt = 0; nt < 8; ++nt) {
        #pragma unroll
        for (int j = 0; j < 4; ++j) {
            size_t rw = rbase + lgrp * 4 + j;
            int col = nt * 16 + lrow;
            float v = acc2[nt][j] + b_p2[col];
            if (col < 64) out[rw * OUT_ + 320 + col] = v;
            else          out[rw * OUT_ + 384 + (col - 64)] = softplusf_(v) + 0.1f;
        }
    }
}

// ---------------------------------------------------------------------------
extern "C" void kernel_launch(void* const* d_in, const int* in_sizes, int n_in,
                              void* d_out, int out_size, void* d_ws, size_t ws_size,
                              hipStream_t stream) {
    const int*   actions = (const int*)  d_in[0];
    const float* obs     = (const float*)d_in[1];
    const float* noise   = (const float*)d_in[2];
    const float* emb     = (const float*)d_in[3];
    const float* w_in    = (const float*)d_in[4];
    const float* b_in    = (const float*)d_in[5];
    const float* g_ln    = (const float*)d_in[6];
    const float* beta_ln = (const float*)d_in[7];
    const float* w_ih    = (const float*)d_in[8];
    const float* b_ih    = (const float*)d_in[9];
    const float* w_hh    = (const float*)d_in[10];
    const float* b_hh    = (const float*)d_in[11];
    const float* w_p1    = (const float*)d_in[12];
    const float* b_p1    = (const float*)d_in[13];
    const float* w_p2    = (const float*)d_in[14];
    const float* b_p2    = (const float*)d_in[15];
    const float* w_q1    = (const float*)d_in[16];
    const float* b_q1    = (const float*)d_in[17];
    const float* w_q2    = (const float*)d_in[18];
    const float* b_q2    = (const float*)d_in[19];

    short* wpk  = (short*)d_ws;
    float* actp = (float*)((char*)d_ws + OFF_ACTP_BYTES);
    float* out  = (float*)d_out;

    auto packLaunch = [&](const float* W, int off, int KT, int rowOff, int srcN, int total) {
        pack_w_kernel<<<(total + 255) / 256, 256, 0, stream>>>(W, wpk + off, KT, rowOff, srcN, total);
    };
    packLaunch(w_in, OFF_WZ,    2, 0,   256, 64 * 256);
    packLaunch(w_ih, OFF_WIH,   8, 0,   768, 256 * 768);
    packLaunch(w_hh, OFF_WHH,   8, 0,   768, 256 * 768);
    packLaunch(w_q1, OFF_WQ1H,  8, 0,   256, 256 * 256);
    packLaunch(w_q1, OFF_WQ1W,  4, 256, 256, 128 * 256);
    packLaunch(w_q2, OFF_WQ2,   8, 0,   128, 256 * 128);
    packLaunch(w_p1, OFF_WP1,   8, 0,   256, 256 * 256);
    packLaunch(w_p2, OFF_WP2,   8, 0,   128, 256 * 128);
    act_proj_kernel<<<NA_, 256, 0, stream>>>(emb, w_in, b_in, actp);

    scan_kernel<<<B_ / RPB, NTH, 0, stream>>>(actions, obs, noise, b_ih, b_hh,
                                              g_ln, beta_ln, b_q1, b_q2, wpk, actp, out);
    prior_kernel<<<(B_ * L_) / 64, 256, 0, stream>>>(b_p1, b_p2, wpk, out);
}

// Round 5
// 4025.791 us; speedup vs baseline: 2.8593x; 1.1822x over previous
//
#include <hip/hip_runtime.h>
#include <hip/hip_bf16.h>

// ---------------------------------------------------------------------------
// RSSM scan on MI355X — round 5: cross-barrier weight streaming.
// 64 blocks x 1024 thr (16 waves, 4/SIMD), RPB=16 rows/block.
// Wave w owns: A nt=w (Wz register-resident); GRU gate-triple {w,16+w,32+w};
// q1 nt=w; q2 (nt=w&7, k-half=w>>3).
// KEY CHANGE vs r4: raw s_barrier (lgkmcnt(0) only, NO vmcnt drain) so weight
// loads stay in flight ACROSS barriers; D+E weight loads issued at end of
// Phase B (fly across 2 barriers + gate VALU); GRU kt0/kt1 issued in Phase A.
// vmcnt waits use ops-issued-after counts with worst-case store placement.
// Frag addr (shorts): F[kt*512 + l*8 + j] = X[row=l&15][k=kt*32+((l>>4)&3)*8+j]
// ---------------------------------------------------------------------------

#define B_   1024
#define L_   256
#define WD_  128
#define AD_  32
#define DD_  256
#define SD_  64
#define HD_  256
#define NA_  17
#define OUT_ 576

typedef __attribute__((ext_vector_type(8))) short bf16x8;
typedef __attribute__((ext_vector_type(4))) float f32x4;
typedef __attribute__((ext_vector_type(2))) float f32x2;

#define OFF_WZ   0
#define OFF_WIH  16384
#define OFF_WHH  212992
#define OFF_WQ1H 409600
#define OFF_WQ1W 475136
#define OFF_WQ2  507904
#define OFF_WP1  540672
#define OFF_WP2  606208
#define PK_TOTAL 638976
#define OFF_ACTP_BYTES (PK_TOTAL * 2)

__device__ __forceinline__ short f2bf(float f) {
    union { float f; unsigned u; } v; v.f = f;
    unsigned r = (v.u + 0x7fffu + ((v.u >> 16) & 1u)) >> 16;  // RNE
    return (short)r;
}

__device__ __forceinline__ f32x4 mfma16(bf16x8 a, bf16x8 b, f32x4 c) {
    return __builtin_amdgcn_mfma_f32_16x16x32_bf16(a, b, c, 0, 0, 0);
}

__device__ __forceinline__ float sigmoidf_(float x) { return 1.f / (1.f + __expf(-x)); }
__device__ __forceinline__ float tanhf_(float x)    { return 2.f / (1.f + __expf(-2.f * x)) - 1.f; }
__device__ __forceinline__ float softplusf_(float x){ return (x > 20.f) ? x : __logf(1.f + __expf(x)); }

__device__ __forceinline__ f32x4 ntload4(const float* p) { return __builtin_nontemporal_load((const f32x4*)p); }
__device__ __forceinline__ void ntstore4(float* p, f32x4 v) { __builtin_nontemporal_store(v, (f32x4*)p); }
__device__ __forceinline__ void ntstoref(float* p, float v) { __builtin_nontemporal_store(v, p); }

template<int IMM>
__device__ __forceinline__ bf16x8 gload(const short* sbase, unsigned voff) {
    bf16x8 d;
    if constexpr (IMM == 0) {
        asm volatile("global_load_dwordx4 %0, %1, %2"
                     : "=v"(d) : "v"(voff), "s"(sbase));
    } else {
        asm volatile("global_load_dwordx4 %0, %1, %2 offset:%3"
                     : "=v"(d) : "v"(voff), "s"(sbase), "i"(IMM));
    }
    return d;
}

#define VMW(N) do { asm volatile("s_waitcnt vmcnt(" #N ")" ::: "memory"); \
                    __builtin_amdgcn_sched_barrier(0); } while (0)

// raw barrier: LDS visibility only — does NOT drain vmcnt (weight stream flies)
#define BAR() do { asm volatile("s_waitcnt lgkmcnt(0)" ::: "memory"); \
                   __builtin_amdgcn_s_barrier(); \
                   __builtin_amdgcn_sched_barrier(0); } while (0)

// ---------------------------------------------------------------------------
__global__ void pack_w_kernel(const float* __restrict__ W, short* __restrict__ dst,
                              int KT, int rowOff, int srcN, int total) {
    int tid = blockIdx.x * 256 + threadIdx.x;
    if (tid >= total) return;
    int j    = tid & 7;
    int lane = (tid >> 3) & 63;
    int kt   = (tid >> 9) % KT;
    int nt   = (tid >> 9) / KT;
    int k = kt * 32 + (lane >> 4) * 8 + j;
    int n = nt * 16 + (lane & 15);
    dst[tid] = f2bf(W[(size_t)(rowOff + k) * srcN + n]);
}

__global__ void act_proj_kernel(const float* __restrict__ emb, const float* __restrict__ w_in,
                                const float* __restrict__ b_in, float* __restrict__ actp) {
    int c = threadIdx.x;
    int a = blockIdx.x;
    float s = b_in[c];
    for (int i = 0; i < AD_; ++i) s += emb[a * AD_ + i] * w_in[(SD_ + i) * HD_ + c];
    actp[a * HD_ + c] = s;
}

// ---------------------------------------------------------------------------
#define RPB 16
#define NTH 1024

template<int KT>
__device__ __forceinline__ void issue6(bf16x8 (&buf)[6],
        const short* ri, const short* ui, const short* ni,
        const short* rh, const short* uh, const short* nh, unsigned voff) {
    constexpr int ADD = (KT >= 4) ? 2048 : 0;   // shorts
    constexpr int IMM = (KT & 3) * 1024;        // bytes
    buf[0] = gload<IMM>(ri + ADD, voff);
    buf[1] = gload<IMM>(ui + ADD, voff);
    buf[2] = gload<IMM>(ni + ADD, voff);
    buf[3] = gload<IMM>(rh + ADD, voff);
    buf[4] = gload<IMM>(uh + ADD, voff);
    buf[5] = gload<IMM>(nh + ADD, voff);
}

__launch_bounds__(NTH, 4)
__global__ void scan_kernel(const int* __restrict__ actions, const float* __restrict__ obs,
                            const float* __restrict__ noise,
                            const float* __restrict__ b_ih, const float* __restrict__ b_hh,
                            const float* __restrict__ g_ln, const float* __restrict__ beta_ln,
                            const float* __restrict__ b_q1, const float* __restrict__ b_q2,
                            const short* __restrict__ wpk, const float* __restrict__ actp,
                            float* __restrict__ out) {
    __shared__ __align__(16) float ps_s [16][20];
    __shared__ __align__(16) float ps_ss[16][20];
    __shared__ __align__(16) float q2p[2][16][132];
    __shared__ __align__(16) short xF  [4096];
    __shared__ __align__(16) short hF  [4096];
    __shared__ __align__(16) short q1F [4096];
    __shared__ __align__(16) short zF  [1024];
    __shared__ __align__(16) short obsF[2048];
    __shared__ __align__(16) float bsumr_l[256], bsumu_l[256], bihn_l[256], bhhn_l[256];
    __shared__ __align__(16) float bq1_l[256], lng_l[256], lnb_l[256], bq2_l[128];

    const int tid  = threadIdx.x;
    const int w    = tid >> 6;          // wave 0..15
    const int lane = tid & 63;
    const int lrow = lane & 15;         // batch row
    const int lgrp = lane >> 4;
    const int row0 = blockIdx.x * RPB;
    const int c0   = w * 16 + lgrp * 4; // lane out-col base
    const int foff = lane * 8;          // frag read offset (shorts)
    const int fwb  = (c0 >> 5) * 512 + (lrow + 16 * ((c0 >> 3) & 3)) * 8 + (c0 & 7);
    const f32x4 zero4 = {0.f, 0.f, 0.f, 0.f};

    const int wu = __builtin_amdgcn_readfirstlane(w);
    const unsigned voff = (unsigned)lane * 16u;
    const short* sbri  = wpk + OFF_WIH  + (wu * 8) * 512;
    const short* sbui  = wpk + OFF_WIH  + ((16 + wu) * 8) * 512;
    const short* sbni  = wpk + OFF_WIH  + ((32 + wu) * 8) * 512;
    const short* sbrh  = wpk + OFF_WHH  + (wu * 8) * 512;
    const short* sbuh  = wpk + OFF_WHH  + ((16 + wu) * 8) * 512;
    const short* sbnh  = wpk + OFF_WHH  + ((32 + wu) * 8) * 512;
    const short* sbq1h = wpk + OFF_WQ1H + (wu * 8) * 512;
    const short* sbq1w = wpk + OFF_WQ1W + (wu * 4) * 512;
    const short* sbq2  = wpk + OFF_WQ2  + ((wu & 7) * 8 + (wu >> 3) * 4) * 512;
    const int khalf = wu >> 3;

    // Wz register-resident (nt = w, KT=2)
    const short* wz = wpk + OFF_WZ;
    const bf16x8 Wz0 = *(const bf16x8*)&wz[(wu * 2 + 0) * 512 + foff];
    const bf16x8 Wz1 = *(const bf16x8*)&wz[(wu * 2 + 1) * 512 + foff];

    // prologue: biases/LN params -> LDS; zero state
    if (tid < 256) {
        bsumr_l[tid] = b_ih[tid] + b_hh[tid];
        bsumu_l[tid] = b_ih[256 + tid] + b_hh[256 + tid];
        bihn_l[tid]  = b_ih[512 + tid];
        bhhn_l[tid]  = b_hh[512 + tid];
        bq1_l[tid]   = b_q1[tid];
        lng_l[tid]   = g_ln[tid];
        lnb_l[tid]   = beta_ln[tid];
    } else if (tid < 384) {
        bq2_l[tid - 256] = b_q2[tid - 256];
    }
    for (int i = tid; i < 4096; i += NTH) hF[i] = 0;
    for (int i = tid; i < 1024; i += NTH) zF[i] = 0;
    f32x4 hreg = zero4;
    __syncthreads();

    for (int t = 0; t < L_; ++t) {
        bf16x8 wb0[6], wb1[6];
        // issue GRU kt0/kt1 immediately — overlaps all of Phase A
        issue6<0>(wb0, sbri, sbui, sbni, sbrh, sbuh, sbnh, voff);
        issue6<1>(wb1, sbri, sbui, sbni, sbrh, sbuh, sbnh, voff);

        // ---- Phase A: xpre = z@Wz + actp[act] (regs); LN partials; obs stage
        f32x4 xp;
        {
            f32x4 a = zero4;
            a = mfma16(Wz0, *(const bf16x8*)&zF[foff], a);
            a = mfma16(Wz1, *(const bf16x8*)&zF[512 + foff], a);
            int act = actions[(row0 + lrow) * L_ + t];
            xp = a + *(const f32x4*)&actp[act * HD_ + c0];
            float s  = xp[0] + xp[1] + xp[2] + xp[3];
            float ss = xp[0]*xp[0] + xp[1]*xp[1] + xp[2]*xp[2] + xp[3]*xp[3];
            s  += __shfl_xor(s, 16, 64);  s  += __shfl_xor(s, 32, 64);
            ss += __shfl_xor(ss, 16, 64); ss += __shfl_xor(ss, 32, 64);
            if (lgrp == 0) { ps_s[lrow][w] = s; ps_ss[lrow][w] = ss; }
            // obs: 16 rows x 128 cols bf16
            int orow = tid >> 6, oc = (tid & 63) * 2;
            f32x2 ov = *(const f32x2*)&obs[((size_t)(row0 + orow) * L_ + t) * WD_ + oc];
            unsigned pk = (unsigned)(unsigned short)f2bf(ov[0])
                        | ((unsigned)(unsigned short)f2bf(ov[1]) << 16);
            *(unsigned*)&obsF[(oc >> 5) * 512 + (orow + 16 * ((oc >> 3) & 3)) * 8 + (oc & 7)] = pk;
        }
        BAR();   // (1)

        // ---- LN finish (per-lane) + xF write --------------------------------
        {
            float s  = ps_s [lrow][lgrp] + ps_s [lrow][lgrp + 4]
                     + ps_s [lrow][lgrp + 8] + ps_s [lrow][lgrp + 12];
            float ss = ps_ss[lrow][lgrp] + ps_ss[lrow][lgrp + 4]
                     + ps_ss[lrow][lgrp + 8] + ps_ss[lrow][lgrp + 12];
            s  += __shfl_xor(s, 16, 64);  s  += __shfl_xor(s, 32, 64);
            ss += __shfl_xor(ss, 16, 64); ss += __shfl_xor(ss, 32, 64);
            float mean = s * (1.f / 256.f);
            float rstd = rsqrtf(ss * (1.f / 256.f) - mean * mean + 1e-5f);
            f32x4 g  = *(const f32x4*)&lng_l[c0];
            f32x4 bb = *(const f32x4*)&lnb_l[c0];
            short4 xb;
            xb.x = f2bf(fmaxf((xp[0] - mean) * rstd * g[0] + bb[0], 0.f));
            xb.y = f2bf(fmaxf((xp[1] - mean) * rstd * g[1] + bb[1], 0.f));
            xb.z = f2bf(fmaxf((xp[2] - mean) * rstd * g[2] + bb[2], 0.f));
            xb.w = f2bf(fmaxf((xp[3] - mean) * rstd * g[3] + bb[3], 0.f));
            *(short4*)&xF[fwb] = xb;
        }
        BAR();   // (2)

        // ---- Phase B: GRU matmuls, 6-wide x depth-2 pipeline ------------------
        f32x4 ar = zero4, au = zero4, aI = zero4, aH = zero4;
#define GRU_KT(KT, WBUF, WN) do { \
        VMW(WN); \
        { bf16x8 xf = *(const bf16x8*)&xF[(KT) * 512 + foff]; \
          bf16x8 hf = *(const bf16x8*)&hF[(KT) * 512 + foff]; \
          ar = mfma16(WBUF[0], xf, ar); ar = mfma16(WBUF[3], hf, ar); \
          au = mfma16(WBUF[1], xf, au); au = mfma16(WBUF[4], hf, au); \
          aI = mfma16(WBUF[2], xf, aI); aH = mfma16(WBUF[5], hf, aH); } \
        if constexpr ((KT) + 2 < 8) \
            issue6<(KT) + 2>(WBUF, sbri, sbui, sbni, sbrh, sbuh, sbnh, voff); \
    } while (0)

        GRU_KT(0, wb0, 6);
        GRU_KT(1, wb1, 6);
        GRU_KT(2, wb0, 6);
        GRU_KT(3, wb1, 6);
        GRU_KT(4, wb0, 6);
        GRU_KT(5, wb1, 6);
        GRU_KT(6, wb0, 6);
        GRU_KT(7, wb1, 0);
#undef GRU_KT

        // issue Phase D (12) + Phase E (4) weight loads — fly across barriers+C
        bf16x8 db[12], eb[4];
        db[0]  = gload<0>   (sbq1h, voff);
        db[1]  = gload<1024>(sbq1h, voff);
        db[2]  = gload<2048>(sbq1h, voff);
        db[3]  = gload<3072>(sbq1h, voff);
        db[4]  = gload<0>   (sbq1h + 2048, voff);
        db[5]  = gload<1024>(sbq1h + 2048, voff);
        db[6]  = gload<2048>(sbq1h + 2048, voff);
        db[7]  = gload<3072>(sbq1h + 2048, voff);
        db[8]  = gload<0>   (sbq1w, voff);
        db[9]  = gload<1024>(sbq1w, voff);
        db[10] = gload<2048>(sbq1w, voff);
        db[11] = gload<3072>(sbq1w, voff);
        eb[0]  = gload<0>   (sbq2, voff);
        eb[1]  = gload<1024>(sbq2, voff);
        eb[2]  = gload<2048>(sbq2, voff);
        eb[3]  = gload<3072>(sbq2, voff);
        BAR();   // (3)  [GRU hF reads done; stream stays in flight]

        // ---- Phase C: gates, h update, hF write, out-h ------------------------
        {
            f32x4 bsr = *(const f32x4*)&bsumr_l[c0];
            f32x4 bsu = *(const f32x4*)&bsumu_l[c0];
            f32x4 bin = *(const f32x4*)&bihn_l[c0];
            f32x4 bhn = *(const f32x4*)&bhhn_l[c0];
            f32x4 hv;
            #pragma unroll
            for (int j = 0; j < 4; ++j) {
                float rr = sigmoidf_(ar[j] + bsr[j]);
                float uu = sigmoidf_(au[j] + bsu[j]);
                float nn = tanhf_(aI[j] + bin[j] + rr * (aH[j] + bhn[j]));
                hv[j] = (1.f - uu) * nn + uu * hreg[j];
            }
            hreg = hv;
            short4 hb;
            hb.x = f2bf(hv[0]); hb.y = f2bf(hv[1]); hb.z = f2bf(hv[2]); hb.w = f2bf(hv[3]);
            *(short4*)&hF[fwb] = hb;
            ntstore4(&out[((size_t)(row0 + lrow) * L_ + t) * OUT_ + c0], hv);
        }
        BAR();   // (4)

        // ---- Phase D: q1 = relu(h@Wq1h + obs@Wq1w + b_q1) ----------------------
        {
            f32x4 aq = zero4;
#define Q1H(KT) { bf16x8 hf = *(const bf16x8*)&hF[(KT) * 512 + foff]; \
                  aq = mfma16(db[KT], hf, aq); }
#define Q1W(KK) { bf16x8 of = *(const bf16x8*)&obsF[(KK) * 512 + foff]; \
                  aq = mfma16(db[8 + (KK)], of, aq); }
            VMW(11);
            Q1H(0) Q1H(1) Q1H(2) Q1H(3)
            VMW(7);
            Q1H(4) Q1H(5) Q1H(6) Q1H(7)
            VMW(3);
            Q1W(0) Q1W(1) Q1W(2) Q1W(3)
#undef Q1H
#undef Q1W
            f32x4 bq = *(const f32x4*)&bq1_l[c0];
            short4 qb;
            qb.x = f2bf(fmaxf(aq[0] + bq[0], 0.f));
            qb.y = f2bf(fmaxf(aq[1] + bq[1], 0.f));
            qb.z = f2bf(fmaxf(aq[2] + bq[2], 0.f));
            qb.w = f2bf(fmaxf(aq[3] + bq[3], 0.f));
            *(short4*)&q1F[fwb] = qb;
        }
        BAR();   // (5)

        // ---- Phase E: q2 partials (nt=w&7, k-half=w>>3) ------------------------
        {
            f32x4 a = zero4;
            VMW(0);
#define Q2K(I) { bf16x8 qf = *(const bf16x8*)&q1F[(khalf * 4 + (I)) * 512 + foff]; \
                 a = mfma16(eb[I], qf, a); }
            Q2K(0) Q2K(1) Q2K(2) Q2K(3)
#undef Q2K
            *(f32x4*)&q2p[khalf][lrow][(wu & 7) * 16 + lgrp * 4] = a;
        }
        BAR();   // (6)

        // ---- Phase F: z sample; out z/qm/qs; zF --------------------------------
        {
            int n = lane;   // wave w = row w
            float qm = q2p[0][w][n]      + q2p[1][w][n]      + bq2_l[n];
            float ql = q2p[0][w][64 + n] + q2p[1][w][64 + n] + bq2_l[64 + n];
            float eps = noise[((size_t)(row0 + w) * L_ + t) * SD_ + n];
            float qs = softplusf_(ql) + 0.1f;
            float zv = qm + qs * eps;
            zF[(n >> 5) * 512 + (w + 16 * ((n >> 3) & 3)) * 8 + (n & 7)] = f2bf(zv);
            size_t ob = ((size_t)(row0 + w) * L_ + t) * OUT_;
            ntstoref(&out[ob + 256 + n], zv);
            ntstoref(&out[ob + 448 + n], qm);
            ntstoref(&out[ob + 512 + n], qs);
        }
        BAR();   // (7)
    }
}

// ---------------------------------------------------------------------------
__launch_bounds__(256, 2)
__global__ void prior_kernel(const float* __restrict__ b_p1, const float* __restrict__ b_p2,
                             const short* __restrict__ wpk, float* __restrict__ out) {
    const short* wp1 = wpk + OFF_WP1;
    const short* wp2 = wpk + OFF_WP2;
    __shared__ __align__(16) short p1b[4][16][264];
    const int tid = threadIdx.x, wid = tid >> 6, lane = tid & 63;
    const int lrow = lane & 15, lgrp = lane >> 4;
    const size_t rbase = (size_t)blockIdx.x * 64 + wid * 16;
    const f32x4 zero4 = {0.f, 0.f, 0.f, 0.f};

    f32x4 acc[16];
    #pragma unroll
    for (int nt = 0; nt < 16; ++nt) acc[nt] = zero4;
    for (int kt = 0; kt < 8; ++kt) {
        const f32x4* hp = (const f32x4*)&out[(rbase + lrow) * OUT_ + kt * 32 + lgrp * 8];
        f32x4 h0 = hp[0], h1 = hp[1];
        bf16x8 a;
        a[0] = f2bf(h0[0]); a[1] = f2bf(h0[1]); a[2] = f2bf(h0[2]); a[3] = f2bf(h0[3]);
        a[4] = f2bf(h1[0]); a[5] = f2bf(h1[1]); a[6] = f2bf(h1[2]); a[7] = f2bf(h1[3]);
        #pragma unroll
        for (int nt = 0; nt < 16; ++nt) {
            bf16x8 b = *(const bf16x8*)&wp1[(nt * 8 + kt) * 512 + lane * 8];
            acc[nt] = mfma16(a, b, acc[nt]);
        }
    }
    #pragma unroll
    for (int nt = 0; nt < 16; ++nt) {
        int colb = nt * 16 + lrow;
        #pragma unroll
        for (int j = 0; j < 4; ++j)
            p1b[wid][lgrp * 4 + j][colb] = f2bf(fmaxf(acc[nt][j] + b_p1[colb], 0.f));
    }
    __syncthreads();

    f32x4 acc2[8];
    #pragma unroll
    for (int nt = 0; nt < 8; ++nt) acc2[nt] = zero4;
    for (int kt = 0; kt < 8; ++kt) {
        bf16x8 a = *(const bf16x8*)&p1b[wid][lrow][kt * 32 + lgrp * 8];
        #pragma unroll
        for (int nt = 0; nt < 8; ++nt) {
            bf16x8 b = *(const bf16x8*)&wp2[(nt * 8 + kt) * 512 + lane * 8];
            acc2[nt] = mfma16(a, b, acc2[nt]);
        }
    }
    #pragma unroll
    for (int nt = 0; nt < 8; ++nt) {
        #pragma unroll
        for (int j = 0; j < 4; ++j) {
            size_t rw = rbase + lgrp * 4 + j;
            int col = nt * 16 + lrow;
            float v = acc2[nt][j] + b_p2[col];
            if (col < 64) out[rw * OUT_ + 320 + col] = v;
            else          out[rw * OUT_ + 384 + (col - 64)] = softplusf_(v) + 0.1f;
        }
    }
}

// ---------------------------------------------------------------------------
extern "C" void kernel_launch(void* const* d_in, const int* in_sizes, int n_in,
                              void* d_out, int out_size, void* d_ws, size_t ws_size,
                              hipStream_t stream) {
    const int*   actions = (const int*)  d_in[0];
    const float* obs     = (const float*)d_in[1];
    const float* noise   = (const float*)d_in[2];
    const float* emb     = (const float*)d_in[3];
    const float* w_in    = (const float*)d_in[4];
    const float* b_in    = (const float*)d_in[5];
    const float* g_ln    = (const float*)d_in[6];
    const float* beta_ln = (const float*)d_in[7];
    const float* w_ih    = (const float*)d_in[8];
    const float* b_ih    = (const float*)d_in[9];
    const float* w_hh    = (const float*)d_in[10];
    const float* b_hh    = (const float*)d_in[11];
    const float* w_p1    = (const float*)d_in[12];
    const float* b_p1    = (const float*)d_in[13];
    const float* w_p2    = (const float*)d_in[14];
    const float* b_p2    = (const float*)d_in[15];
    const float* w_q1    = (const float*)d_in[16];
    const float* b_q1    = (const float*)d_in[17];
    const float* w_q2    = (const float*)d_in[18];
    const float* b_q2    = (const float*)d_in[19];

    short* wpk  = (short*)d_ws;
    float* actp = (float*)((char*)d_ws + OFF_ACTP_BYTES);
    float* out  = (float*)d_out;

    auto packLaunch = [&](const float* W, int off, int KT, int rowOff, int srcN, int total) {
        pack_w_kernel<<<(total + 255) / 256, 256, 0, stream>>>(W, wpk + off, KT, rowOff, srcN, total);
    };
    packLaunch(w_in, OFF_WZ,    2, 0,   256, 64 * 256);
    packLaunch(w_ih, OFF_WIH,   8, 0,   768, 256 * 768);
    packLaunch(w_hh, OFF_WHH,   8, 0,   768, 256 * 768);
    packLaunch(w_q1, OFF_WQ1H,  8, 0,   256, 256 * 256);
    packLaunch(w_q1, OFF_WQ1W,  4, 256, 256, 128 * 256);
    packLaunch(w_q2, OFF_WQ2,   8, 0,   128, 256 * 128);
    packLaunch(w_p1, OFF_WP1,   8, 0,   256, 256 * 256);
    packLaunch(w_p2, OFF_WP2,   8, 0,   128, 256 * 128);
    act_proj_kernel<<<NA_, 256, 0, stream>>>(emb, w_in, b_in, actp);

    scan_kernel<<<B_ / RPB, NTH, 0, stream>>>(actions, obs, noise, b_ih, b_hh,
                                              g_ln, beta_ln, b_q1, b_q2, wpk, actp, out);
    prior_kernel<<<(B_ * L_) / 64, 256, 0, stream>>>(b_p1, b_p2, wpk, out);
}

// Round 6
// 3976.834 us; speedup vs baseline: 2.8945x; 1.0123x over previous
//
#include <hip/hip_runtime.h>
#include <hip/hip_bf16.h>

// ---------------------------------------------------------------------------
// RSSM scan on MI355X — round 6: 100% hand-counted VMEM in the t-loop.
// 64 blocks x 1024 thr (16 waves, 4/SIMD), RPB=16 rows/block.
// r5 failure: compiler-emitted global loads (actions/actp/obs/noise) inserted
// their own vmcnt waits that drained the hand-counted weight stream twice per
// step. r6: actions+actp live in LDS (prologue); obs/noise are counted asm
// loads; all out-stores are counted asm nt-stores issued at the end of F and
// drained by A's VMW(12) next step. Every VMEM op in the loop is in the ledger:
//   TOP: [obs 1][gru k0 6][gru k1 6]          (+4 stores still flying from F)
//   A:   VMW(12) -> obs ready (drains stores too)
//   B:   kt0..6: VMW(6); kt7: VMW(0); then issue [db 12][eb 4][noise 1]
//   D:   VMW(13)/VMW(9)/VMW(5)   E: VMW(1)   F: VMW(0); issue 4 stores
// Frag addr (shorts): F[kt*512 + l*8 + j] = X[row=l&15][k=kt*32+((l>>4)&3)*8+j]
// ---------------------------------------------------------------------------

#define B_   1024
#define L_   256
#define WD_  128
#define AD_  32
#define DD_  256
#define SD_  64
#define HD_  256
#define NA_  17
#define OUT_ 576

typedef __attribute__((ext_vector_type(8))) short bf16x8;
typedef __attribute__((ext_vector_type(4))) float f32x4;
typedef __attribute__((ext_vector_type(2))) float f32x2;

#define OFF_WZ   0
#define OFF_WIH  16384
#define OFF_WHH  212992
#define OFF_WQ1H 409600
#define OFF_WQ1W 475136
#define OFF_WQ2  507904
#define OFF_WP1  540672
#define OFF_WP2  606208
#define PK_TOTAL 638976
#define OFF_ACTP_BYTES (PK_TOTAL * 2)

__device__ __forceinline__ short f2bf(float f) {
    union { float f; unsigned u; } v; v.f = f;
    unsigned r = (v.u + 0x7fffu + ((v.u >> 16) & 1u)) >> 16;  // RNE
    return (short)r;
}

__device__ __forceinline__ f32x4 mfma16(bf16x8 a, bf16x8 b, f32x4 c) {
    return __builtin_amdgcn_mfma_f32_16x16x32_bf16(a, b, c, 0, 0, 0);
}

__device__ __forceinline__ float sigmoidf_(float x) { return 1.f / (1.f + __expf(-x)); }
__device__ __forceinline__ float tanhf_(float x)    { return 2.f / (1.f + __expf(-2.f * x)) - 1.f; }
__device__ __forceinline__ float softplusf_(float x){ return (x > 20.f) ? x : __logf(1.f + __expf(x)); }

// ---- counted asm VMEM ops (SGPR base + unsigned VGPR byte offset) ----------
template<int IMM>
__device__ __forceinline__ bf16x8 gload(const short* sbase, unsigned voff) {
    bf16x8 d;
    if constexpr (IMM == 0) {
        asm volatile("global_load_dwordx4 %0, %1, %2"
                     : "=v"(d) : "v"(voff), "s"(sbase));
    } else {
        asm volatile("global_load_dwordx4 %0, %1, %2 offset:%3"
                     : "=v"(d) : "v"(voff), "s"(sbase), "i"(IMM));
    }
    return d;
}
__device__ __forceinline__ f32x2 gload2f(const float* sbase, unsigned voff) {
    f32x2 d;
    asm volatile("global_load_dwordx2 %0, %1, %2 nt" : "=v"(d) : "v"(voff), "s"(sbase));
    return d;
}
__device__ __forceinline__ float gload1f(const float* sbase, unsigned voff) {
    float d;
    asm volatile("global_load_dword %0, %1, %2 nt" : "=v"(d) : "v"(voff), "s"(sbase));
    return d;
}
__device__ __forceinline__ void gstore4f(float* sbase, unsigned voff, f32x4 v) {
    asm volatile("global_store_dwordx4 %0, %1, %2 nt" :: "v"(voff), "v"(v), "s"(sbase));
}
__device__ __forceinline__ void gstore1f(float* sbase, unsigned voff, float v) {
    asm volatile("global_store_dword %0, %1, %2 nt" :: "v"(voff), "v"(v), "s"(sbase));
}

#define VMW(N) do { asm volatile("s_waitcnt vmcnt(" #N ")" ::: "memory"); \
                    __builtin_amdgcn_sched_barrier(0); } while (0)

// raw barrier: LDS visibility only — does NOT drain vmcnt
#define BAR() do { asm volatile("s_waitcnt lgkmcnt(0)" ::: "memory"); \
                   __builtin_amdgcn_s_barrier(); \
                   __builtin_amdgcn_sched_barrier(0); } while (0)

// ---------------------------------------------------------------------------
__global__ void pack_w_kernel(const float* __restrict__ W, short* __restrict__ dst,
                              int KT, int rowOff, int srcN, int total) {
    int tid = blockIdx.x * 256 + threadIdx.x;
    if (tid >= total) return;
    int j    = tid & 7;
    int lane = (tid >> 3) & 63;
    int kt   = (tid >> 9) % KT;
    int nt   = (tid >> 9) / KT;
    int k = kt * 32 + (lane >> 4) * 8 + j;
    int n = nt * 16 + (lane & 15);
    dst[tid] = f2bf(W[(size_t)(rowOff + k) * srcN + n]);
}

__global__ void act_proj_kernel(const float* __restrict__ emb, const float* __restrict__ w_in,
                                const float* __restrict__ b_in, float* __restrict__ actp) {
    int c = threadIdx.x;
    int a = blockIdx.x;
    float s = b_in[c];
    for (int i = 0; i < AD_; ++i) s += emb[a * AD_ + i] * w_in[(SD_ + i) * HD_ + c];
    actp[a * HD_ + c] = s;
}

// ---------------------------------------------------------------------------
#define RPB 16
#define NTH 1024

template<int KT>
__device__ __forceinline__ void issue6(bf16x8 (&buf)[6],
        const short* ri, const short* ui, const short* ni,
        const short* rh, const short* uh, const short* nh, unsigned voff) {
    constexpr int ADD = (KT >= 4) ? 2048 : 0;   // shorts
    constexpr int IMM = (KT & 3) * 1024;        // bytes
    buf[0] = gload<IMM>(ri + ADD, voff);
    buf[1] = gload<IMM>(ui + ADD, voff);
    buf[2] = gload<IMM>(ni + ADD, voff);
    buf[3] = gload<IMM>(rh + ADD, voff);
    buf[4] = gload<IMM>(uh + ADD, voff);
    buf[5] = gload<IMM>(nh + ADD, voff);
}

__launch_bounds__(NTH, 4)
__global__ void scan_kernel(const int* __restrict__ actions, const float* __restrict__ obs,
                            const float* __restrict__ noise,
                            const float* __restrict__ b_ih, const float* __restrict__ b_hh,
                            const float* __restrict__ g_ln, const float* __restrict__ beta_ln,
                            const float* __restrict__ b_q1, const float* __restrict__ b_q2,
                            const short* __restrict__ wpk, const float* __restrict__ actp,
                            float* __restrict__ out) {
    __shared__ __align__(16) float ps_s [16][20];
    __shared__ __align__(16) float ps_ss[16][20];
    __shared__ __align__(16) float q2p[2][16][132];
    __shared__ __align__(16) short xF  [4096];
    __shared__ __align__(16) short hF  [4096];
    __shared__ __align__(16) short q1F [4096];
    __shared__ __align__(16) short zF  [1024];
    __shared__ __align__(16) short obsF[2048];
    __shared__ __align__(16) float bq1_l[256], lng_l[256], lnb_l[256], bq2_l[128];
    __shared__ __align__(16) int   act_l[L_][16];       // [t][row] — conflict-free read
    __shared__ __align__(16) float actp_l[NA_][260];    // +4 pad -> 2-way max

    const int tid  = threadIdx.x;
    const int w    = tid >> 6;          // wave 0..15
    const int lane = tid & 63;
    const int lrow = lane & 15;         // batch row
    const int lgrp = lane >> 4;
    const int row0 = blockIdx.x * RPB;
    const int c0   = w * 16 + lgrp * 4; // lane out-col base
    const int foff = lane * 8;          // frag read offset (shorts)
    const int fwb  = (c0 >> 5) * 512 + (lrow + 16 * ((c0 >> 3) & 3)) * 8 + (c0 & 7);
    const f32x4 zero4 = {0.f, 0.f, 0.f, 0.f};

    const int wu = __builtin_amdgcn_readfirstlane(w);
    const unsigned voff = (unsigned)lane * 16u;
    const short* sbri  = wpk + OFF_WIH  + (wu * 8) * 512;
    const short* sbui  = wpk + OFF_WIH  + ((16 + wu) * 8) * 512;
    const short* sbni  = wpk + OFF_WIH  + ((32 + wu) * 8) * 512;
    const short* sbrh  = wpk + OFF_WHH  + (wu * 8) * 512;
    const short* sbuh  = wpk + OFF_WHH  + ((16 + wu) * 8) * 512;
    const short* sbnh  = wpk + OFF_WHH  + ((32 + wu) * 8) * 512;
    const short* sbq1h = wpk + OFF_WQ1H + (wu * 8) * 512;
    const short* sbq1w = wpk + OFF_WQ1W + (wu * 4) * 512;
    const short* sbq2  = wpk + OFF_WQ2  + ((wu & 7) * 8 + (wu >> 3) * 4) * 512;
    const int khalf = wu >> 3;

    // Wz register-resident (nt = w, KT=2)
    const short* wz = wpk + OFF_WZ;
    const bf16x8 Wz0 = *(const bf16x8*)&wz[(wu * 2 + 0) * 512 + foff];
    const bf16x8 Wz1 = *(const bf16x8*)&wz[(wu * 2 + 1) * 512 + foff];

    // gate biases -> registers (C phase becomes pure VALU)
    f32x4 bsr = *(const f32x4*)&b_ih[c0]       + *(const f32x4*)&b_hh[c0];
    f32x4 bsu = *(const f32x4*)&b_ih[256 + c0] + *(const f32x4*)&b_hh[256 + c0];
    f32x4 bin = *(const f32x4*)&b_ih[512 + c0];
    f32x4 bhn = *(const f32x4*)&b_hh[512 + c0];

    // prologue: params + actions + actp -> LDS; zero state
    if (tid < 256) {
        bq1_l[tid] = b_q1[tid];
        lng_l[tid] = g_ln[tid];
        lnb_l[tid] = beta_ln[tid];
    } else if (tid < 384) {
        bq2_l[tid - 256] = b_q2[tid - 256];
    }
    for (int i = tid; i < RPB * L_; i += NTH) {
        int r = i >> 8, tt = i & 255;
        act_l[tt][r] = actions[(row0 + r) * L_ + tt];
    }
    for (int i = tid; i < NA_ * HD_; i += NTH) {
        actp_l[i >> 8][i & 255] = actp[i];
    }
    for (int i = tid; i < 4096; i += NTH) hF[i] = 0;
    for (int i = tid; i < 1024; i += NTH) zF[i] = 0;
    f32x4 hreg = zero4;

    // strength-reduced global byte offsets
    unsigned obs_off = (unsigned)((row0 + w) * L_) * (WD_ * 4u) + (unsigned)lane * 8u;
    unsigned nz_off  = (unsigned)((row0 + w) * L_) * (SD_ * 4u) + (unsigned)lane * 4u;
    unsigned ho_off  = (unsigned)((row0 + lrow) * L_) * (OUT_ * 4u) + (unsigned)c0 * 4u;
    unsigned zo_off  = (unsigned)((row0 + w) * L_) * (OUT_ * 4u);
    __syncthreads();   // drains prologue vmcnt -> ledger starts at 0

    for (int t = 0; t < L_; ++t) {
        // ---- TOP: issue obs(1) + GRU kt0(6) + kt1(6) --------------------------
        f32x2 obsv = gload2f(obs, obs_off);
        bf16x8 wb0[6], wb1[6];
        issue6<0>(wb0, sbri, sbui, sbni, sbrh, sbuh, sbnh, voff);
        issue6<1>(wb1, sbri, sbui, sbni, sbrh, sbuh, sbnh, voff);

        // ---- Phase A: xpre = z@Wz + actp_l[act]; LN partials; obsF stage -----
        f32x4 xp;
        {
            f32x4 a = zero4;
            a = mfma16(Wz0, *(const bf16x8*)&zF[foff], a);
            a = mfma16(Wz1, *(const bf16x8*)&zF[512 + foff], a);
            int act = act_l[t][lrow];
            xp = a + *(const f32x4*)&actp_l[act][c0];
            float s  = xp[0] + xp[1] + xp[2] + xp[3];
            float ss = xp[0]*xp[0] + xp[1]*xp[1] + xp[2]*xp[2] + xp[3]*xp[3];
            s  += __shfl_xor(s, 16, 64);  s  += __shfl_xor(s, 32, 64);
            ss += __shfl_xor(ss, 16, 64); ss += __shfl_xor(ss, 32, 64);
            if (lgrp == 0) { ps_s[lrow][w] = s; ps_ss[lrow][w] = ss; }
        }
        // obs consume: outstanding = st(4,prev F)+obs(1)+k0(6)+k1(6)=17 -> VMW(12)
        VMW(12);
        {
            int oc = lane * 2;   // wave w = batch row w
            unsigned pk = (unsigned)(unsigned short)f2bf(obsv[0])
                        | ((unsigned)(unsigned short)f2bf(obsv[1]) << 16);
            *(unsigned*)&obsF[(oc >> 5) * 512 + (w + 16 * ((oc >> 3) & 3)) * 8 + (oc & 7)] = pk;
        }
        BAR();   // (1)

        // ---- LN finish (per-lane) + xF write ---------------------------------
        {
            float s  = ps_s [lrow][lgrp] + ps_s [lrow][lgrp + 4]
                     + ps_s [lrow][lgrp + 8] + ps_s [lrow][lgrp + 12];
            float ss = ps_ss[lrow][lgrp] + ps_ss[lrow][lgrp + 4]
                     + ps_ss[lrow][lgrp + 8] + ps_ss[lrow][lgrp + 12];
            s  += __shfl_xor(s, 16, 64);  s  += __shfl_xor(s, 32, 64);
            ss += __shfl_xor(ss, 16, 64); ss += __shfl_xor(ss, 32, 64);
            float mean = s * (1.f / 256.f);
            float rstd = rsqrtf(ss * (1.f / 256.f) - mean * mean + 1e-5f);
            f32x4 g  = *(const f32x4*)&lng_l[c0];
            f32x4 bb = *(const f32x4*)&lnb_l[c0];
            short4 xb;
            xb.x = f2bf(fmaxf((xp[0] - mean) * rstd * g[0] + bb[0], 0.f));
            xb.y = f2bf(fmaxf((xp[1] - mean) * rstd * g[1] + bb[1], 0.f));
            xb.z = f2bf(fmaxf((xp[2] - mean) * rstd * g[2] + bb[2], 0.f));
            xb.w = f2bf(fmaxf((xp[3] - mean) * rstd * g[3] + bb[3], 0.f));
            *(short4*)&xF[fwb] = xb;
        }
        BAR();   // (2)

        // ---- Phase B: GRU matmuls, 6-wide x depth-2 pipeline ------------------
        f32x4 ar = zero4, au = zero4, aI = zero4, aH = zero4;
#define GRU_KT(KT, WBUF, WN) do { \
        VMW(WN); \
        { bf16x8 xf = *(const bf16x8*)&xF[(KT) * 512 + foff]; \
          bf16x8 hf = *(const bf16x8*)&hF[(KT) * 512 + foff]; \
          ar = mfma16(WBUF[0], xf, ar); ar = mfma16(WBUF[3], hf, ar); \
          au = mfma16(WBUF[1], xf, au); au = mfma16(WBUF[4], hf, au); \
          aI = mfma16(WBUF[2], xf, aI); aH = mfma16(WBUF[5], hf, aH); } \
        if constexpr ((KT) + 2 < 8) \
            issue6<(KT) + 2>(WBUF, sbri, sbui, sbni, sbrh, sbuh, sbnh, voff); \
    } while (0)

        GRU_KT(0, wb0, 6);
        GRU_KT(1, wb1, 6);
        GRU_KT(2, wb0, 6);
        GRU_KT(3, wb1, 6);
        GRU_KT(4, wb0, 6);
        GRU_KT(5, wb1, 6);
        GRU_KT(6, wb0, 6);
        GRU_KT(7, wb1, 0);
#undef GRU_KT

        // issue Phase D (12) + Phase E (4) + noise (1) — fly across C
        bf16x8 db[12], eb[4];
        db[0]  = gload<0>   (sbq1h, voff);
        db[1]  = gload<1024>(sbq1h, voff);
        db[2]  = gload<2048>(sbq1h, voff);
        db[3]  = gload<3072>(sbq1h, voff);
        db[4]  = gload<0>   (sbq1h + 2048, voff);
        db[5]  = gload<1024>(sbq1h + 2048, voff);
        db[6]  = gload<2048>(sbq1h + 2048, voff);
        db[7]  = gload<3072>(sbq1h + 2048, voff);
        db[8]  = gload<0>   (sbq1w, voff);
        db[9]  = gload<1024>(sbq1w, voff);
        db[10] = gload<2048>(sbq1w, voff);
        db[11] = gload<3072>(sbq1w, voff);
        eb[0]  = gload<0>   (sbq2, voff);
        eb[1]  = gload<1024>(sbq2, voff);
        eb[2]  = gload<2048>(sbq2, voff);
        eb[3]  = gload<3072>(sbq2, voff);
        float nzv = gload1f(noise, nz_off);
        BAR();   // (3)  [GRU hF/xF reads done; 17 loads in flight]

        // ---- Phase C: gates (pure VALU), hF write -----------------------------
        {
            f32x4 hv;
            #pragma unroll
            for (int j = 0; j < 4; ++j) {
                float rr = sigmoidf_(ar[j] + bsr[j]);
                float uu = sigmoidf_(au[j] + bsu[j]);
                float nn = tanhf_(aI[j] + bin[j] + rr * (aH[j] + bhn[j]));
                hv[j] = (1.f - uu) * nn + uu * hreg[j];
            }
            hreg = hv;
            short4 hb;
            hb.x = f2bf(hv[0]); hb.y = f2bf(hv[1]); hb.z = f2bf(hv[2]); hb.w = f2bf(hv[3]);
            *(short4*)&hF[fwb] = hb;
        }
        BAR();   // (4)

        // ---- Phase D: q1 = relu(h@Wq1h + obs@Wq1w + b_q1) ----------------------
        {
            f32x4 aq = zero4;
#define Q1H(KT) { bf16x8 hf = *(const bf16x8*)&hF[(KT) * 512 + foff]; \
                  aq = mfma16(db[KT], hf, aq); }
#define Q1W(KK) { bf16x8 of = *(const bf16x8*)&obsF[(KK) * 512 + foff]; \
                  aq = mfma16(db[8 + (KK)], of, aq); }
            VMW(13);
            Q1H(0) Q1H(1) Q1H(2) Q1H(3)
            VMW(9);
            Q1H(4) Q1H(5) Q1H(6) Q1H(7)
            VMW(5);
            Q1W(0) Q1W(1) Q1W(2) Q1W(3)
#undef Q1H
#undef Q1W
            f32x4 bq = *(const f32x4*)&bq1_l[c0];
            short4 qb;
            qb.x = f2bf(fmaxf(aq[0] + bq[0], 0.f));
            qb.y = f2bf(fmaxf(aq[1] + bq[1], 0.f));
            qb.z = f2bf(fmaxf(aq[2] + bq[2], 0.f));
            qb.w = f2bf(fmaxf(aq[3] + bq[3], 0.f));
            *(short4*)&q1F[fwb] = qb;
        }
        BAR();   // (5)

        // ---- Phase E: q2 partials (nt=w&7, k-half=w>>3) ------------------------
        {
            f32x4 a = zero4;
            VMW(1);
#define Q2K(I) { bf16x8 qf = *(const bf16x8*)&q1F[(khalf * 4 + (I)) * 512 + foff]; \
                 a = mfma16(eb[I], qf, a); }
            Q2K(0) Q2K(1) Q2K(2) Q2K(3)
#undef Q2K
            *(f32x4*)&q2p[khalf][lrow][(wu & 7) * 16 + lgrp * 4] = a;
        }
        BAR();   // (6)

        // ---- Phase F: z sample; zF write; counted out-stores (4) ---------------
        {
            int n = lane;   // wave w = row w
            VMW(0);         // noise ready; stream fully drained
            float qm = q2p[0][w][n]      + q2p[1][w][n]      + bq2_l[n];
            float ql = q2p[0][w][64 + n] + q2p[1][w][64 + n] + bq2_l[64 + n];
            float qs = softplusf_(ql) + 0.1f;
            float zv = qm + qs * nzv;
            zF[(n >> 5) * 512 + (w + 16 * ((n >> 3) & 3)) * 8 + (n & 7)] = f2bf(zv);
            unsigned zo = zo_off + (unsigned)t * (OUT_ * 4u);
            gstore4f(out, ho_off + (unsigned)t * (OUT_ * 4u), hreg);
            gstore1f(out, zo + (256 + n) * 4u, zv);
            gstore1f(out, zo + (448 + n) * 4u, qm);
            gstore1f(out, zo + (512 + n) * 4u, qs);
        }
        BAR();   // (7)
        obs_off += WD_ * 4u;
        nz_off  += SD_ * 4u;
    }
    asm volatile("s_waitcnt vmcnt(0)" ::: "memory");
}

// ---------------------------------------------------------------------------
__launch_bounds__(256, 2)
__global__ void prior_kernel(const float* __restrict__ b_p1, const float* __restrict__ b_p2,
                             const short* __restrict__ wpk, float* __restrict__ out) {
    const short* wp1 = wpk + OFF_WP1;
    const short* wp2 = wpk + OFF_WP2;
    __shared__ __align__(16) short p1b[4][16][264];
    const int tid = threadIdx.x, wid = tid >> 6, lane = tid & 63;
    const int lrow = lane & 15, lgrp = lane >> 4;
    const size_t rbase = (size_t)blockIdx.x * 64 + wid * 16;
    const f32x4 zero4 = {0.f, 0.f, 0.f, 0.f};

    f32x4 acc[16];
    #pragma unroll
    for (int nt = 0; nt < 16; ++nt) acc[nt] = zero4;
    for (int kt = 0; kt < 8; ++kt) {
        const f32x4* hp = (const f32x4*)&out[(rbase + lrow) * OUT_ + kt * 32 + lgrp * 8];
        f32x4 h0 = hp[0], h1 = hp[1];
        bf16x8 a;
        a[0] = f2bf(h0[0]); a[1] = f2bf(h0[1]); a[2] = f2bf(h0[2]); a[3] = f2bf(h0[3]);
        a[4] = f2bf(h1[0]); a[5] = f2bf(h1[1]); a[6] = f2bf(h1[2]); a[7] = f2bf(h1[3]);
        #pragma unroll
        for (int nt = 0; nt < 16; ++nt) {
            bf16x8 b = *(const bf16x8*)&wp1[(nt * 8 + kt) * 512 + lane * 8];
            acc[nt] = mfma16(a, b, acc[nt]);
        }
    }
    #pragma unroll
    for (int nt = 0; nt < 16; ++nt) {
        int colb = nt * 16 + lrow;
        #pragma unroll
        for (int j = 0; j < 4; ++j)
            p1b[wid][lgrp * 4 + j][colb] = f2bf(fmaxf(acc[nt][j] + b_p1[colb], 0.f));
    }
    __syncthreads();

    f32x4 acc2[8];
    #pragma unroll
    for (int nt = 0; nt < 8; ++nt) acc2[nt] = zero4;
    for (int kt = 0; kt < 8; ++kt) {
        bf16x8 a = *(const bf16x8*)&p1b[wid][lrow][kt * 32 + lgrp * 8];
        #pragma unroll
        for (int nt = 0; nt < 8; ++nt) {
            bf16x8 b = *(const bf16x8*)&wp2[(nt * 8 + kt) * 512 + lane * 8];
            acc2[nt] = mfma16(a, b, acc2[nt]);
        }
    }
    #pragma unroll
    for (int nt = 0; nt < 8; ++nt) {
        #pragma unroll
        for (int j = 0; j < 4; ++j) {
            size_t rw = rbase + lgrp * 4 + j;
            int col = nt * 16 + lrow;
            float v = acc2[nt][j] + b_p2[col];
            if (col < 64) out[rw * OUT_ + 320 + col] = v;
            else          out[rw * OUT_ + 384 + (col - 64)] = softplusf_(v) + 0.1f;
        }
    }
}

// ---------------------------------------------------------------------------
extern "C" void kernel_launch(void* const* d_in, const int* in_sizes, int n_in,
                              void* d_out, int out_size, void* d_ws, size_t ws_size,
                              hipStream_t stream) {
    const int*   actions = (const int*)  d_in[0];
    const float* obs     = (const float*)d_in[1];
    const float* noise   = (const float*)d_in[2];
    const float* emb     = (const float*)d_in[3];
    const float* w_in    = (const float*)d_in[4];
    const float* b_in    = (const float*)d_in[5];
    const float* g_ln    = (const float*)d_in[6];
    const float* beta_ln = (const float*)d_in[7];
    const float* w_ih    = (const float*)d_in[8];
    const float* b_ih    = (const float*)d_in[9];
    const float* w_hh    = (const float*)d_in[10];
    const float* b_hh    = (const float*)d_in[11];
    const float* w_p1    = (const float*)d_in[12];
    const float* b_p1    = (const float*)d_in[13];
    const float* w_p2    = (const float*)d_in[14];
    const float* b_p2    = (const float*)d_in[15];
    const float* w_q1    = (const float*)d_in[16];
    const float* b_q1    = (const float*)d_in[17];
    const float* w_q2    = (const float*)d_in[18];
    const float* b_q2    = (const float*)d_in[19];

    short* wpk  = (short*)d_ws;
    float* actp = (float*)((char*)d_ws + OFF_ACTP_BYTES);
    float* out  = (float*)d_out;

    auto packLaunch = [&](const float* W, int off, int KT, int rowOff, int srcN, int total) {
        pack_w_kernel<<<(total + 255) / 256, 256, 0, stream>>>(W, wpk + off, KT, rowOff, srcN, total);
    };
    packLaunch(w_in, OFF_WZ,    2, 0,   256, 64 * 256);
    packLaunch(w_ih, OFF_WIH,   8, 0,   768, 256 * 768);
    packLaunch(w_hh, OFF_WHH,   8, 0,   768, 256 * 768);
    packLaunch(w_q1, OFF_WQ1H,  8, 0,   256, 256 * 256);
    packLaunch(w_q1, OFF_WQ1W,  4, 256, 256, 128 * 256);
    packLaunch(w_q2, OFF_WQ2,   8, 0,   128, 256 * 128);
    packLaunch(w_p1, OFF_WP1,   8, 0,   256, 256 * 256);
    packLaunch(w_p2, OFF_WP2,   8, 0,   128, 256 * 128);
    act_proj_kernel<<<NA_, 256, 0, stream>>>(emb, w_in, b_in, actp);

    scan_kernel<<<B_ / RPB, NTH, 0, stream>>>(actions, obs, noise, b_ih, b_hh,
                                              g_ln, beta_ln, b_q1, b_q2, wpk, actp, out);
    prior_kernel<<<(B_ * L_) / 64, 256, 0, stream>>>(b_p1, b_p2, wpk, out);
}

// Round 7
// 3690.429 us; speedup vs baseline: 3.1191x; 1.0776x over previous
//
#include <hip/hip_runtime.h>
#include <hip/hip_bf16.h>

// ---------------------------------------------------------------------------
// RSSM scan on MI355X — round 7: continuous cross-step weight stream.
// 64 blocks x 1024 thr (16 waves, 4/SIMD), RPB=16 rows/block.
// r6 residuals fixed: (1) compiler-loaded regs (biases, Wz) pinned via asm in
// the prologue so NO compiler vmcnt lands inside the loop; (2) ledger never
// drains: next-step obs+GRU kt0/kt1 issued at end of D, db split-issued at
// kt6/kt7, E/F use counted waits. Min outstanding = 5.
// Steady-state queue (oldest->newest) at phase entry:
//   A:  [obs1 k0'6 k1'6 st4]=17        VMW(16) -> obs
//   B:  kt0 VMW(10), kt1 VMW(10), kt2..7 VMW(6); kt6 issues db0..5,
//       kt7 issues db6..11+eb4+nz -> 17
//   D:  VMW(13)/(9)/(5); then issue obs'(1) k0'(6) k1'(6) -> 18
//   E:  VMW(14) -> eb      F: VMW(13) -> nz; issue st4 -> 17
// Frag addr (shorts): F[kt*512 + l*8 + j] = X[row=l&15][k=kt*32+((l>>4)&3)*8+j]
// ---------------------------------------------------------------------------

#define B_   1024
#define L_   256
#define WD_  128
#define AD_  32
#define DD_  256
#define SD_  64
#define HD_  256
#define NA_  17
#define OUT_ 576

typedef __attribute__((ext_vector_type(8))) short bf16x8;
typedef __attribute__((ext_vector_type(4))) float f32x4;
typedef __attribute__((ext_vector_type(2))) float f32x2;
typedef __attribute__((ext_vector_type(2))) unsigned u32x2;

#define OFF_WZ   0
#define OFF_WIH  16384
#define OFF_WHH  212992
#define OFF_WQ1H 409600
#define OFF_WQ1W 475136
#define OFF_WQ2  507904
#define OFF_WP1  540672
#define OFF_WP2  606208
#define PK_TOTAL 638976
#define OFF_ACTP_BYTES (PK_TOTAL * 2)
#define OFF_DSCR_BYTES (OFF_ACTP_BYTES + 32768)

__device__ __forceinline__ short f2bf(float f) {
    union { float f; unsigned u; } v; v.f = f;
    unsigned r = (v.u + 0x7fffu + ((v.u >> 16) & 1u)) >> 16;  // RNE
    return (short)r;
}
__device__ __forceinline__ unsigned cvtpk(float a, float b) {
    unsigned r;
    asm("v_cvt_pk_bf16_f32 %0, %1, %2" : "=v"(r) : "v"(a), "v"(b));
    return r;
}

__device__ __forceinline__ f32x4 mfma16(bf16x8 a, bf16x8 b, f32x4 c) {
    return __builtin_amdgcn_mfma_f32_16x16x32_bf16(a, b, c, 0, 0, 0);
}

__device__ __forceinline__ float sigmoidf_(float x) { return 1.f / (1.f + __expf(-x)); }
__device__ __forceinline__ float tanhf_(float x)    { return 2.f / (1.f + __expf(-2.f * x)) - 1.f; }
__device__ __forceinline__ float softplusf_(float x){ return (x > 20.f) ? x : __logf(1.f + __expf(x)); }

// ---- counted asm VMEM (SGPR base + unsigned VGPR byte offset) --------------
template<int IMM>
__device__ __forceinline__ bf16x8 gload(const short* sbase, unsigned voff) {
    bf16x8 d;
    if constexpr (IMM == 0) {
        asm volatile("global_load_dwordx4 %0, %1, %2"
                     : "=v"(d) : "v"(voff), "s"(sbase));
    } else {
        asm volatile("global_load_dwordx4 %0, %1, %2 offset:%3"
                     : "=v"(d) : "v"(voff), "s"(sbase), "i"(IMM));
    }
    return d;
}
__device__ __forceinline__ f32x2 gload2f(const float* sbase, unsigned voff) {
    f32x2 d;
    asm volatile("global_load_dwordx2 %0, %1, %2 nt" : "=v"(d) : "v"(voff), "s"(sbase));
    return d;
}
__device__ __forceinline__ float gload1f(const float* sbase, unsigned voff) {
    float d;
    asm volatile("global_load_dword %0, %1, %2 nt" : "=v"(d) : "v"(voff), "s"(sbase));
    return d;
}
__device__ __forceinline__ void gstore4f(float* sbase, unsigned voff, f32x4 v) {
    asm volatile("global_store_dwordx4 %0, %1, %2 nt" :: "v"(voff), "v"(v), "s"(sbase));
}
__device__ __forceinline__ void gstore1f(float* sbase, unsigned voff, float v) {
    asm volatile("global_store_dword %0, %1, %2 nt" :: "v"(voff), "v"(v), "s"(sbase));
}

#define VMW(N) do { asm volatile("s_waitcnt vmcnt(" #N ")" ::: "memory"); \
                    __builtin_amdgcn_sched_barrier(0); } while (0)

// raw barrier: LDS visibility only — does NOT drain vmcnt
#define BAR() do { asm volatile("s_waitcnt lgkmcnt(0)" ::: "memory"); \
                   __builtin_amdgcn_s_barrier(); \
                   __builtin_amdgcn_sched_barrier(0); } while (0)

// ---------------------------------------------------------------------------
__global__ void pack_w_kernel(const float* __restrict__ W, short* __restrict__ dst,
                              int KT, int rowOff, int srcN, int total) {
    int tid = blockIdx.x * 256 + threadIdx.x;
    if (tid >= total) return;
    int j    = tid & 7;
    int lane = (tid >> 3) & 63;
    int kt   = (tid >> 9) % KT;
    int nt   = (tid >> 9) / KT;
    int k = kt * 32 + (lane >> 4) * 8 + j;
    int n = nt * 16 + (lane & 15);
    dst[tid] = f2bf(W[(size_t)(rowOff + k) * srcN + n]);
}

__global__ void act_proj_kernel(const float* __restrict__ emb, const float* __restrict__ w_in,
                                const float* __restrict__ b_in, float* __restrict__ actp) {
    int c = threadIdx.x;
    int a = blockIdx.x;
    float s = b_in[c];
    for (int i = 0; i < AD_; ++i) s += emb[a * AD_ + i] * w_in[(SD_ + i) * HD_ + c];
    actp[a * HD_ + c] = s;
}

// ---------------------------------------------------------------------------
#define RPB 16
#define NTH 1024

template<int KT>
__device__ __forceinline__ void issue6(bf16x8 (&buf)[6],
        const short* ri, const short* ui, const short* ni,
        const short* rh, const short* uh, const short* nh, unsigned voff) {
    constexpr int ADD = (KT >= 4) ? 2048 : 0;   // shorts
    constexpr int IMM = (KT & 3) * 1024;        // bytes
    buf[0] = gload<IMM>(ri + ADD, voff);
    buf[1] = gload<IMM>(ui + ADD, voff);
    buf[2] = gload<IMM>(ni + ADD, voff);
    buf[3] = gload<IMM>(rh + ADD, voff);
    buf[4] = gload<IMM>(uh + ADD, voff);
    buf[5] = gload<IMM>(nh + ADD, voff);
}

__launch_bounds__(NTH, 4)
__global__ void scan_kernel(const int* __restrict__ actions, const float* __restrict__ obs,
                            const float* __restrict__ noise,
                            const float* __restrict__ b_ih, const float* __restrict__ b_hh,
                            const float* __restrict__ g_ln, const float* __restrict__ beta_ln,
                            const float* __restrict__ b_q1, const float* __restrict__ b_q2,
                            const short* __restrict__ wpk, const float* __restrict__ actp,
                            float* __restrict__ dscr, float* __restrict__ out) {
    __shared__ __align__(16) float ps_s [16][20];
    __shared__ __align__(16) float ps_ss[16][20];
    __shared__ __align__(16) float q2p[2][16][132];
    __shared__ __align__(16) short xF  [4096];
    __shared__ __align__(16) short hF  [4096];
    __shared__ __align__(16) short q1F [4096];
    __shared__ __align__(16) short zF  [1024];
    __shared__ __align__(16) short obsF[2048];
    __shared__ __align__(16) float bq1_l[256], lng_l[256], lnb_l[256], bq2_l[128];
    __shared__ __align__(16) int   act_l[L_][16];
    __shared__ __align__(16) float actp_l[NA_][260];

    const int tid  = threadIdx.x;
    const int w    = tid >> 6;
    const int lane = tid & 63;
    const int lrow = lane & 15;
    const int lgrp = lane >> 4;
    const int row0 = blockIdx.x * RPB;
    const int c0   = w * 16 + lgrp * 4;
    const int foff = lane * 8;
    const int fwb  = (c0 >> 5) * 512 + (lrow + 16 * ((c0 >> 3) & 3)) * 8 + (c0 & 7);
    const f32x4 zero4 = {0.f, 0.f, 0.f, 0.f};

    const int wu = __builtin_amdgcn_readfirstlane(w);
    const unsigned voff = (unsigned)lane * 16u;
    const short* sbri  = wpk + OFF_WIH  + (wu * 8) * 512;
    const short* sbui  = wpk + OFF_WIH  + ((16 + wu) * 8) * 512;
    const short* sbni  = wpk + OFF_WIH  + ((32 + wu) * 8) * 512;
    const short* sbrh  = wpk + OFF_WHH  + (wu * 8) * 512;
    const short* sbuh  = wpk + OFF_WHH  + ((16 + wu) * 8) * 512;
    const short* sbnh  = wpk + OFF_WHH  + ((32 + wu) * 8) * 512;
    const short* sbq1h = wpk + OFF_WQ1H + (wu * 8) * 512;
    const short* sbq1w = wpk + OFF_WQ1W + (wu * 4) * 512;
    const short* sbq2  = wpk + OFF_WQ2  + ((wu & 7) * 8 + (wu >> 3) * 4) * 512;
    const int khalf = wu >> 3;

    // Wz register-resident (nt = w, KT=2)
    const short* wz = wpk + OFF_WZ;
    const bf16x8 Wz0 = *(const bf16x8*)&wz[(wu * 2 + 0) * 512 + foff];
    const bf16x8 Wz1 = *(const bf16x8*)&wz[(wu * 2 + 1) * 512 + foff];

    // gate biases -> registers
    f32x4 bsr = *(const f32x4*)&b_ih[c0]       + *(const f32x4*)&b_hh[c0];
    f32x4 bsu = *(const f32x4*)&b_ih[256 + c0] + *(const f32x4*)&b_hh[256 + c0];
    f32x4 bin = *(const f32x4*)&b_ih[512 + c0];
    f32x4 bhn = *(const f32x4*)&b_hh[512 + c0];
    // PIN: force compiler waitcnt for these loads to land HERE, not in the loop
    asm volatile("" :: "v"(bsr), "v"(bsu), "v"(bin), "v"(bhn), "v"(Wz0), "v"(Wz1));

    // prologue: params + actions + actp -> LDS; zero state
    if (tid < 256) {
        bq1_l[tid] = b_q1[tid];
        lng_l[tid] = g_ln[tid];
        lnb_l[tid] = beta_ln[tid];
    } else if (tid < 384) {
        bq2_l[tid - 256] = b_q2[tid - 256];
    }
    for (int i = tid; i < RPB * L_; i += NTH) {
        int r = i >> 8, tt = i & 255;
        act_l[tt][r] = actions[(row0 + r) * L_ + tt];
    }
    for (int i = tid; i < NA_ * HD_; i += NTH) {
        actp_l[i >> 8][i & 255] = actp[i];
    }
    for (int i = tid; i < 4096; i += NTH) hF[i] = 0;
    for (int i = tid; i < 1024; i += NTH) zF[i] = 0;
    f32x4 hreg = zero4;

    unsigned obs_off = (unsigned)((row0 + w) * L_) * (WD_ * 4u) + (unsigned)lane * 8u;
    unsigned nz_off  = (unsigned)((row0 + w) * L_) * (SD_ * 4u) + (unsigned)lane * 4u;
    unsigned ho_off  = (unsigned)((row0 + lrow) * L_) * (OUT_ * 4u) + (unsigned)c0 * 4u;
    unsigned zo_off  = (unsigned)((row0 + w) * L_) * (OUT_ * 4u);
    __syncthreads();   // drains prologue VMEM; ledger starts at 0 (self-aligns)

    // persistent stream buffers (live across iterations)
    bf16x8 wb0[6], wb1[6], db[12], eb[4];
    f32x2 obsv;
    float nzv;

    // PRE-ISSUE steady-state queue: obs, k0, k1, 4 dummy stores  -> 17
    obsv = gload2f(obs, obs_off);
    issue6<0>(wb0, sbri, sbui, sbni, sbrh, sbuh, sbnh, voff);
    issue6<1>(wb1, sbri, sbui, sbni, sbrh, sbuh, sbnh, voff);
    {
        unsigned doff = (unsigned)tid * 16u;
        gstore4f(dscr, doff, zero4);
        gstore4f(dscr, doff + 16384u, zero4);
        gstore4f(dscr, doff + 32768u, zero4);
        gstore4f(dscr, doff + 49152u, zero4);
    }

    for (int t = 0; t < L_; ++t) {
        // ---- Phase A: xpre = z@Wz + actp_l[act]; LN partials; obsF stage ----
        f32x4 xp;
        {
            f32x4 a = zero4;
            a = mfma16(Wz0, *(const bf16x8*)&zF[foff], a);
            a = mfma16(Wz1, *(const bf16x8*)&zF[512 + foff], a);
            int act = act_l[t][lrow];
            xp = a + *(const f32x4*)&actp_l[act][c0];
            float s  = xp[0] + xp[1] + xp[2] + xp[3];
            float ss = xp[0]*xp[0] + xp[1]*xp[1] + xp[2]*xp[2] + xp[3]*xp[3];
            s  += __shfl_xor(s, 16, 64);  s  += __shfl_xor(s, 32, 64);
            ss += __shfl_xor(ss, 16, 64); ss += __shfl_xor(ss, 32, 64);
            if (lgrp == 0) { ps_s[lrow][w] = s; ps_ss[lrow][w] = ss; }
        }
        VMW(16);   // obs ready (k0,k1,st still flying)
        {
            int oc = lane * 2;   // wave w = batch row w
            *(unsigned*)&obsF[(oc >> 5) * 512 + (w + 16 * ((oc >> 3) & 3)) * 8 + (oc & 7)]
                = cvtpk(obsv[0], obsv[1]);
        }
        BAR();   // (1)

        // ---- LN finish (per-lane) + xF write --------------------------------
        {
            float s  = ps_s [lrow][lgrp] + ps_s [lrow][lgrp + 4]
                     + ps_s [lrow][lgrp + 8] + ps_s [lrow][lgrp + 12];
            float ss = ps_ss[lrow][lgrp] + ps_ss[lrow][lgrp + 4]
                     + ps_ss[lrow][lgrp + 8] + ps_ss[lrow][lgrp + 12];
            s  += __shfl_xor(s, 16, 64);  s  += __shfl_xor(s, 32, 64);
            ss += __shfl_xor(ss, 16, 64); ss += __shfl_xor(ss, 32, 64);
            float mean = s * (1.f / 256.f);
            float rstd = rsqrtf(ss * (1.f / 256.f) - mean * mean + 1e-5f);
            f32x4 g  = *(const f32x4*)&lng_l[c0];
            f32x4 bb = *(const f32x4*)&lnb_l[c0];
            u32x2 xb;
            xb[0] = cvtpk(fmaxf((xp[0] - mean) * rstd * g[0] + bb[0], 0.f),
                          fmaxf((xp[1] - mean) * rstd * g[1] + bb[1], 0.f));
            xb[1] = cvtpk(fmaxf((xp[2] - mean) * rstd * g[2] + bb[2], 0.f),
                          fmaxf((xp[3] - mean) * rstd * g[3] + bb[3], 0.f));
            *(u32x2*)&xF[fwb] = xb;
        }
        BAR();   // (2)

        // ---- Phase B: GRU matmuls, continuous stream -------------------------
        f32x4 ar = zero4, au = zero4, aI = zero4, aH = zero4;
#define GRU_MFMA(KT, WBUF) { \
        bf16x8 xf = *(const bf16x8*)&xF[(KT) * 512 + foff]; \
        bf16x8 hf = *(const bf16x8*)&hF[(KT) * 512 + foff]; \
        ar = mfma16(WBUF[0], xf, ar); ar = mfma16(WBUF[3], hf, ar); \
        au = mfma16(WBUF[1], xf, au); au = mfma16(WBUF[4], hf, au); \
        aI = mfma16(WBUF[2], xf, aI); aH = mfma16(WBUF[5], hf, aH); }

        VMW(10); GRU_MFMA(0, wb0);
        issue6<2>(wb0, sbri, sbui, sbni, sbrh, sbuh, sbnh, voff);
        VMW(10); GRU_MFMA(1, wb1);
        issue6<3>(wb1, sbri, sbui, sbni, sbrh, sbuh, sbnh, voff);
        VMW(6);  GRU_MFMA(2, wb0);
        issue6<4>(wb0, sbri, sbui, sbni, sbrh, sbuh, sbnh, voff);
        VMW(6);  GRU_MFMA(3, wb1);
        issue6<5>(wb1, sbri, sbui, sbni, sbrh, sbuh, sbnh, voff);
        VMW(6);  GRU_MFMA(4, wb0);
        issue6<6>(wb0, sbri, sbui, sbni, sbrh, sbuh, sbnh, voff);
        VMW(6);  GRU_MFMA(5, wb1);
        issue6<7>(wb1, sbri, sbui, sbni, sbrh, sbuh, sbnh, voff);
        VMW(6);  GRU_MFMA(6, wb0);
        db[0]  = gload<0>   (sbq1h, voff);          // kt6 slot: issue db0..5
        db[1]  = gload<1024>(sbq1h, voff);
        db[2]  = gload<2048>(sbq1h, voff);
        db[3]  = gload<3072>(sbq1h, voff);
        db[4]  = gload<0>   (sbq1h + 2048, voff);
        db[5]  = gload<1024>(sbq1h + 2048, voff);
        VMW(6);  GRU_MFMA(7, wb1);
        db[6]  = gload<2048>(sbq1h + 2048, voff);   // kt7 slot: db6..11 + eb + nz
        db[7]  = gload<3072>(sbq1h + 2048, voff);
        db[8]  = gload<0>   (sbq1w, voff);
        db[9]  = gload<1024>(sbq1w, voff);
        db[10] = gload<2048>(sbq1w, voff);
        db[11] = gload<3072>(sbq1w, voff);
        eb[0]  = gload<0>   (sbq2, voff);
        eb[1]  = gload<1024>(sbq2, voff);
        eb[2]  = gload<2048>(sbq2, voff);
        eb[3]  = gload<3072>(sbq2, voff);
        nzv    = gload1f(noise, nz_off);
        nz_off += SD_ * 4u;
#undef GRU_MFMA
        BAR();   // (3)

        // ---- Phase C: gates (pure VALU), hF write -----------------------------
        {
            f32x4 hv;
            #pragma unroll
            for (int j = 0; j < 4; ++j) {
                float rr = sigmoidf_(ar[j] + bsr[j]);
                float uu = sigmoidf_(au[j] + bsu[j]);
                float nn = tanhf_(aI[j] + bin[j] + rr * (aH[j] + bhn[j]));
                hv[j] = (1.f - uu) * nn + uu * hreg[j];
            }
            hreg = hv;
            u32x2 hb;
            hb[0] = cvtpk(hv[0], hv[1]);
            hb[1] = cvtpk(hv[2], hv[3]);
            *(u32x2*)&hF[fwb] = hb;
        }
        BAR();   // (4)

        // ---- Phase D: q1 = relu(h@Wq1h + obs@Wq1w + b_q1) ----------------------
        {
            f32x4 aq = zero4;
#define Q1H(KT) { bf16x8 hf = *(const bf16x8*)&hF[(KT) * 512 + foff]; \
                  aq = mfma16(db[KT], hf, aq); }
#define Q1W(KK) { bf16x8 of = *(const bf16x8*)&obsF[(KK) * 512 + foff]; \
                  aq = mfma16(db[8 + (KK)], of, aq); }
            VMW(13);
            Q1H(0) Q1H(1) Q1H(2) Q1H(3)
            VMW(9);
            Q1H(4) Q1H(5) Q1H(6) Q1H(7)
            VMW(5);
            Q1W(0) Q1W(1) Q1W(2) Q1W(3)
#undef Q1H
#undef Q1W
            f32x4 bq = *(const f32x4*)&bq1_l[c0];
            u32x2 qb;
            qb[0] = cvtpk(fmaxf(aq[0] + bq[0], 0.f), fmaxf(aq[1] + bq[1], 0.f));
            qb[1] = cvtpk(fmaxf(aq[2] + bq[2], 0.f), fmaxf(aq[3] + bq[3], 0.f));
            *(u32x2*)&q1F[fwb] = qb;
        }
        // prefetch NEXT step: obs', GRU k0', k1'  (t=255: clamp obs, weights same)
        {
            unsigned onext = obs_off + ((t < L_ - 1) ? (WD_ * 4u) : 0u);
            obsv = gload2f(obs, onext);
            obs_off = onext;
            issue6<0>(wb0, sbri, sbui, sbni, sbrh, sbuh, sbnh, voff);
            issue6<1>(wb1, sbri, sbui, sbni, sbrh, sbuh, sbnh, voff);
        }
        BAR();   // (5)

        // ---- Phase E: q2 partials (nt=w&7, k-half=w>>3) ------------------------
        {
            f32x4 a = zero4;
            VMW(14);   // eb ready (nz + obs' + k0' + k1' = 14 behind)
#define Q2K(I) { bf16x8 qf = *(const bf16x8*)&q1F[(khalf * 4 + (I)) * 512 + foff]; \
                 a = mfma16(eb[I], qf, a); }
            Q2K(0) Q2K(1) Q2K(2) Q2K(3)
#undef Q2K
            *(f32x4*)&q2p[khalf][lrow][(wu & 7) * 16 + lgrp * 4] = a;
        }
        BAR();   // (6)

        // ---- Phase F: z sample; zF write; counted out-stores -------------------
        {
            int n = lane;   // wave w = row w
            VMW(13);        // nz ready (obs'1 + k0'6 + k1'6 = 13 behind)
            float qm = q2p[0][w][n]      + q2p[1][w][n]      + bq2_l[n];
            float ql = q2p[0][w][64 + n] + q2p[1][w][64 + n] + bq2_l[64 + n];
            float qs = softplusf_(ql) + 0.1f;
            float zv = qm + qs * nzv;
            zF[(n >> 5) * 512 + (w + 16 * ((n >> 3) & 3)) * 8 + (n & 7)] = f2bf(zv);
            unsigned zo = zo_off;
            gstore4f(out, ho_off, hreg);
            gstore1f(out, zo + (256 + n) * 4u, zv);
            gstore1f(out, zo + (448 + n) * 4u, qm);
            gstore1f(out, zo + (512 + n) * 4u, qs);
        }
        BAR();   // (7)
        ho_off += OUT_ * 4u;
        zo_off += OUT_ * 4u;
    }
    asm volatile("s_waitcnt vmcnt(0)" ::: "memory");
}

// ---------------------------------------------------------------------------
__launch_bounds__(256, 2)
__global__ void prior_kernel(const float* __restrict__ b_p1, const float* __restrict__ b_p2,
                             const short* __restrict__ wpk, float* __restrict__ out) {
    const short* wp1 = wpk + OFF_WP1;
    const short* wp2 = wpk + OFF_WP2;
    __shared__ __align__(16) short p1b[4][16][264];
    const int tid = threadIdx.x, wid = tid >> 6, lane = tid & 63;
    const int lrow = lane & 15, lgrp = lane >> 4;
    const size_t rbase = (size_t)blockIdx.x * 64 + wid * 16;
    const f32x4 zero4 = {0.f, 0.f, 0.f, 0.f};

    f32x4 acc[16];
    #pragma unroll
    for (int nt = 0; nt < 16; ++nt) acc[nt] = zero4;
    for (int kt = 0; kt < 8; ++kt) {
        const f32x4* hp = (const f32x4*)&out[(rbase + lrow) * OUT_ + kt * 32 + lgrp * 8];
        f32x4 h0 = hp[0], h1 = hp[1];
        bf16x8 a;
        a[0] = f2bf(h0[0]); a[1] = f2bf(h0[1]); a[2] = f2bf(h0[2]); a[3] = f2bf(h0[3]);
        a[4] = f2bf(h1[0]); a[5] = f2bf(h1[1]); a[6] = f2bf(h1[2]); a[7] = f2bf(h1[3]);
        #pragma unroll
        for (int nt = 0; nt < 16; ++nt) {
            bf16x8 b = *(const bf16x8*)&wp1[(nt * 8 + kt) * 512 + lane * 8];
            acc[nt] = mfma16(a, b, acc[nt]);
        }
    }
    #pragma unroll
    for (int nt = 0; nt < 16; ++nt) {
        int colb = nt * 16 + lrow;
        #pragma unroll
        for (int j = 0; j < 4; ++j)
            p1b[wid][lgrp * 4 + j][colb] = f2bf(fmaxf(acc[nt][j] + b_p1[colb], 0.f));
    }
    __syncthreads();

    f32x4 acc2[8];
    #pragma unroll
    for (int nt = 0; nt < 8; ++nt) acc2[nt] = zero4;
    for (int kt = 0; kt < 8; ++kt) {
        bf16x8 a = *(const bf16x8*)&p1b[wid][lrow][kt * 32 + lgrp * 8];
        #pragma unroll
        for (int nt = 0; nt < 8; ++nt) {
            bf16x8 b = *(const bf16x8*)&wp2[(nt * 8 + kt) * 512 + lane * 8];
            acc2[nt] = mfma16(a, b, acc2[nt]);
        }
    }
    #pragma unroll
    for (int nt = 0; nt < 8; ++nt) {
        #pragma unroll
        for (int j = 0; j < 4; ++j) {
            size_t rw = rbase + lgrp * 4 + j;
            int col = nt * 16 + lrow;
            float v = acc2[nt][j] + b_p2[col];
            if (col < 64) out[rw * OUT_ + 320 + col] = v;
            else          out[rw * OUT_ + 384 + (col - 64)] = softplusf_(v) + 0.1f;
        }
    }
}

// ---------------------------------------------------------------------------
extern "C" void kernel_launch(void* const* d_in, const int* in_sizes, int n_in,
                              void* d_out, int out_size, void* d_ws, size_t ws_size,
                              hipStream_t stream) {
    const int*   actions = (const int*)  d_in[0];
    const float* obs     = (const float*)d_in[1];
    const float* noise   = (const float*)d_in[2];
    const float* emb     = (const float*)d_in[3];
    const float* w_in    = (const float*)d_in[4];
    const float* b_in    = (const float*)d_in[5];
    const float* g_ln    = (const float*)d_in[6];
    const float* beta_ln = (const float*)d_in[7];
    const float* w_ih    = (const float*)d_in[8];
    const float* b_ih    = (const float*)d_in[9];
    const float* w_hh    = (const float*)d_in[10];
    const float* b_hh    = (const float*)d_in[11];
    const float* w_p1    = (const float*)d_in[12];
    const float* b_p1    = (const float*)d_in[13];
    const float* w_p2    = (const float*)d_in[14];
    const float* b_p2    = (const float*)d_in[15];
    const float* w_q1    = (const float*)d_in[16];
    const float* b_q1    = (const float*)d_in[17];
    const float* w_q2    = (const float*)d_in[18];
    const float* b_q2    = (const float*)d_in[19];

    short* wpk  = (short*)d_ws;
    float* actp = (float*)((char*)d_ws + OFF_ACTP_BYTES);
    float* dscr = (float*)((char*)d_ws + OFF_DSCR_BYTES);
    float* out  = (float*)d_out;

    auto packLaunch = [&](const float* W, int off, int KT, int rowOff, int srcN, int total) {
        pack_w_kernel<<<(total + 255) / 256, 256, 0, stream>>>(W, wpk + off, KT, rowOff, srcN, total);
    };
    packLaunch(w_in, OFF_WZ,    2, 0,   256, 64 * 256);
    packLaunch(w_ih, OFF_WIH,   8, 0,   768, 256 * 768);
    packLaunch(w_hh, OFF_WHH,   8, 0,   768, 256 * 768);
    packLaunch(w_q1, OFF_WQ1H,  8, 0,   256, 256 * 256);
    packLaunch(w_q1, OFF_WQ1W,  4, 256, 256, 128 * 256);
    packLaunch(w_q2, OFF_WQ2,   8, 0,   128, 256 * 128);
    packLaunch(w_p1, OFF_WP1,   8, 0,   256, 256 * 256);
    packLaunch(w_p2, OFF_WP2,   8, 0,   128, 256 * 128);
    act_proj_kernel<<<NA_, 256, 0, stream>>>(emb, w_in, b_in, actp);

    scan_kernel<<<B_ / RPB, NTH, 0, stream>>>(actions, obs, noise, b_ih, b_hh,
                                              g_ln, beta_ln, b_q1, b_q2, wpk, actp, dscr, out);
    prior_kernel<<<(B_ * L_) / 64, 256, 0, stream>>>(b_p1, b_p2, wpk, out);
}